// Round 3
// baseline (523.525 us; speedup 1.0000x reference)
//
#include <hip/hip_runtime.h>
#include <hip/hip_bf16.h>
#include <cmath>

#define T_ 512
#define B_ 32
#define S_ 512
#define D_ 512
#define D3_ 1536
#define NCH 16
#define CT (T_ / NCH)
static constexpr float LN_EPS = 1e-6f;
static constexpr float RSQRT_D = 0.044194173824159216f; // 1/sqrt(512)

typedef __attribute__((ext_vector_type(8))) __bf16 bf16x8;
typedef __attribute__((ext_vector_type(4))) float f32x4;

struct __align__(8) bfx4 { __hip_bfloat16 x, y, z, w; };

// ---------------- async global->LDS, 16B per lane ---------------------------
__device__ __forceinline__ void g2l16(const void* g, void* l) {
    __builtin_amdgcn_global_load_lds(
        (const __attribute__((address_space(1))) unsigned int*)g,
        (__attribute__((address_space(3))) unsigned int*)l, 16, 0, 0);
}

// 16-lane xor reductions (lanes sharing lane>>4 quad reduce over lane&15)
__device__ __forceinline__ float xr_sum16(float v) {
    v += __shfl_xor(v, 1); v += __shfl_xor(v, 2);
    v += __shfl_xor(v, 4); v += __shfl_xor(v, 8); return v;
}
__device__ __forceinline__ float xr_max16(float v) {
    v = fmaxf(v, __shfl_xor(v, 1)); v = fmaxf(v, __shfl_xor(v, 2));
    v = fmaxf(v, __shfl_xor(v, 4)); v = fmaxf(v, __shfl_xor(v, 8)); return v;
}

__device__ __forceinline__ float sigmoidf_(float x) {
    return 1.f / (1.f + __expf(-x));
}
// fast variants for the fused epilogue only (error ~1e-6, saturates right)
__device__ __forceinline__ float sigmoid_fast(float x) {
    return __fdividef(1.f, 1.f + __expf(-x));
}
__device__ __forceinline__ float tanh_fast(float x) {
    return 1.f - __fdividef(2.f, __expf(2.f * x) + 1.f);
}
__device__ __forceinline__ float bfu(unsigned short u) {
    unsigned int v = ((unsigned int)u) << 16;
    return __uint_as_float(v);
}

// =============== K1: preact GEMM 128x128, double-buffered ===================
// A = prevb [16384,512] bf16, B = W_inT [1536,512] bf16.
// Double-buffered LDS (one barrier per K-step) + XCD-aware grid swizzle so
// each XCD owns contiguous row-panels (A-panel L2 locality, nwg=1536%8==0).
// Writes preb bf16 [16384,1536] (LDS-repacked coalesced) + per-block row
// (sum,sumsq) partials for the 1536-wide LayerNorm.
__global__ __launch_bounds__(256) void gemm_pre(
    const __hip_bfloat16* __restrict__ A,
    const __hip_bfloat16* __restrict__ Bw,
    __hip_bfloat16* __restrict__ preb,
    float2* __restrict__ part)
{
    __shared__ char smem[32768];   // 2 x (A 8KB | B 8KB)

    const int lin = blockIdx.y * 12 + blockIdx.x;       // dispatch order
    const int swz = (lin & 7) * 192 + (lin >> 3);       // XCD-contiguous
    const int bx = swz % 12, by = swz / 12;
    const int m0 = by * 128, n0 = bx * 128;
    const int tid = threadIdx.x, lane = tid & 63, w = tid >> 6;
    const int wm = (w >> 1) * 64, wn = (w & 1) * 64;
    const int srow = lane >> 2, skB = (lane & 3) * 16;
    const int q = lane >> 4, c = lane & 15;

    f32x4 acc[4][4];
#pragma unroll
    for (int i = 0; i < 4; i++)
#pragma unroll
        for (int j = 0; j < 4; j++) acc[i][j] = (f32x4)(0.0f);

    const char* ga0 = (const char*)(A + (long)(m0 + w * 16 + srow) * 512) + skB;
    const char* ga1 = (const char*)(A + (long)(m0 + (w + 4) * 16 + srow) * 512) + skB;
    const char* gb0 = (const char*)(Bw + (long)(n0 + w * 16 + srow) * 512) + skB;
    const char* gb1 = (const char*)(Bw + (long)(n0 + (w + 4) * 16 + srow) * 512) + skB;
    char* la0 = smem + w * 1024 + lane * 16;
    char* la1 = smem + (w + 4) * 1024 + lane * 16;
    char* lb0 = smem + 8192 + w * 1024 + lane * 16;
    char* lb1 = smem + 8192 + (w + 4) * 1024 + lane * 16;
    const char* Ar = smem + (wm + c) * 64 + q * 16;
    const char* Br = smem + 8192 + (wn + c) * 64 + q * 16;

    // prologue: stage K-tile 0 into buffer 0
    g2l16(ga0, la0);
    g2l16(ga1, la1);
    g2l16(gb0, lb0);
    g2l16(gb1, lb1);
    __syncthreads();

#pragma unroll
    for (int kk = 0; kk < 16; kk++) {
        const int cb = (kk & 1) << 14;       // current buffer (0 / 16384)
        const int nb = cb ^ 16384;           // next buffer
        if (kk < 15) {
            const long kb = (long)(kk + 1) * 64;   // 32 k-elems * 2B
            g2l16(ga0 + kb, la0 + nb);
            g2l16(ga1 + kb, la1 + nb);
            g2l16(gb0 + kb, lb0 + nb);
            g2l16(gb1 + kb, lb1 + nb);
        }
        bf16x8 af[4], bfr[4];
#pragma unroll
        for (int i = 0; i < 4; i++) {
            af[i] = *(const bf16x8*)(Ar + cb + i * 1024);
            bfr[i] = *(const bf16x8*)(Br + cb + i * 1024);
        }
#pragma unroll
        for (int i = 0; i < 4; i++)
#pragma unroll
            for (int j = 0; j < 4; j++)
                acc[i][j] = __builtin_amdgcn_mfma_f32_16x16x32_bf16(
                    af[i], bfr[j], acc[i][j], 0, 0, 0);
        __syncthreads();   // waves done with buf cb; prefetch into nb landed
    }

    // ---- row stats partials (sum, sumsq over this block's 128 cols) ----
    float2* sred = (float2*)smem;        // [128][2]
#pragma unroll
    for (int i = 0; i < 4; i++)
#pragma unroll
        for (int r = 0; r < 4; r++) {
            float s = 0.f, qq = 0.f;
#pragma unroll
            for (int j = 0; j < 4; j++) {
                float v = acc[i][j][r]; s += v; qq += v * v;
            }
            s = xr_sum16(s); qq = xr_sum16(qq);
            if (c == 0) sred[(wm + i * 16 + q * 4 + r) * 2 + (w & 1)] =
                make_float2(s, qq);
        }
    __syncthreads();
    if ((w & 1) == 0 && c == 0) {
#pragma unroll
        for (int i = 0; i < 4; i++)
#pragma unroll
            for (int r = 0; r < 4; r++) {
                int row = wm + i * 16 + q * 4 + r;
                float2 a = sred[row * 2], b2 = sred[row * 2 + 1];
                part[(long)bx * 16384 + m0 + row] =
                    make_float2(a.x + b2.x, a.y + b2.y);
            }
    }
    __syncthreads();

    // ---- bf16 store via LDS repack (2 passes of 64 rows x 128 cols) ----
    for (int p = 0; p < 2; p++) {
        if ((w >> 1) == p) {
#pragma unroll
            for (int i = 0; i < 4; i++)
#pragma unroll
                for (int j = 0; j < 4; j++)
#pragma unroll
                    for (int r = 0; r < 4; r++) {
                        int row = i * 16 + q * 4 + r;
                        int col = wn + j * 16 + c;
                        ((__hip_bfloat16*)smem)[row * 128 + col] =
                            __float2bfloat16(acc[i][j][r]);
                    }
        }
        __syncthreads();
#pragma unroll
        for (int rnd = 0; rnd < 4; rnd++) {
            int row = rnd * 16 + (tid >> 4);
            int ch = tid & 15;
            uint4 v = *(const uint4*)(smem + row * 256 + ch * 16);
            long grow = m0 + p * 64 + row;
            *(uint4*)((char*)preb + grow * 3072 + (long)n0 * 2 + ch * 16) = v;
        }
        __syncthreads();
    }
}

// =============== fused-row GEMM core: 32 rows x full N=512, K=512 ===========
// REGISTER-DIRECT: each wave's B-slice (rows w*128..w*128+127) is private —
// LDS staging gave zero inter-wave B reuse, so it was pure overhead (LDS
// write+read BW and a vmcnt(0)+barrier per K-step). Each lane now loads its
// exact MFMA fragment with global_load_dwordx4; no LDS, no barriers in the
// K-loop; the fully unrolled loop lets the compiler pipeline loads across
// K-steps. Fragment addressing identical to the old LDS-read math:
//   af[m]  = A[(m*16 + (lane&15))*lda + k0 .. ], 16B chunk (lane>>4)
//   bfr[j] = B[(w*128 + j*16 + (lane&15))*ldb + k0 ..], chunk (lane>>4)
// acc[m][j]: row = m*16 + (lane>>4)*4 + r, col = w*128 + j*16 + (lane&15).
__device__ __forceinline__ void rows_core32(
    const __hip_bfloat16* __restrict__ A, long lda,
    const __hip_bfloat16* __restrict__ B, long ldb,
    f32x4 (&acc)[2][8])
{
    const int lane = threadIdx.x & 63, w = threadIdx.x >> 6;
    const int fr = lane & 15;          // fragment row within 16
    const int kq = lane >> 4;          // 16B k-chunk within 64B k-step
#pragma unroll
    for (int m = 0; m < 2; m++)
#pragma unroll
        for (int j = 0; j < 8; j++) acc[m][j] = (f32x4)(0.0f);

    const char* a0 = (const char*)(A + (long)fr * lda) + kq * 16;
    const char* a1 = (const char*)(A + (long)(16 + fr) * lda) + kq * 16;
    const char* b0 = (const char*)(B + (long)(w * 128 + fr) * ldb) + kq * 16;
    const long ldbB16 = (long)ldb * 32;   // 16 B-rows in bytes

#pragma unroll
    for (int kk = 0; kk < 16; kk++) {
        const long kb = (long)kk * 64;     // 32 k-elems * 2B
        bf16x8 af[2], bfr[8];
        af[0] = *(const bf16x8*)(a0 + kb);
        af[1] = *(const bf16x8*)(a1 + kb);
#pragma unroll
        for (int j = 0; j < 8; j++)
            bfr[j] = *(const bf16x8*)(b0 + kb + j * ldbB16);
#pragma unroll
        for (int m = 0; m < 2; m++)
#pragma unroll
            for (int j = 0; j < 8; j++)
                acc[m][j] = __builtin_amdgcn_mfma_f32_16x16x32_bf16(
                    af[m], bfr[j], acc[m][j], 0, 0, 0);
    }
}

// =============== K2/K3/K6: GEMM + row LayerNorm -> bf16 (1KB rows) ==========
__global__ __launch_bounds__(256, 2) void gemm_ln(
    const __hip_bfloat16* __restrict__ A, long lda,
    const __hip_bfloat16* __restrict__ W,
    const float* __restrict__ g, const float* __restrict__ bb,
    __hip_bfloat16* __restrict__ out)
{
    __shared__ char smem[32768];
    const long m0 = (long)blockIdx.y * 32;
    f32x4 acc[2][8];
    rows_core32(A + m0 * lda, lda, W, 512, acc);

    const int tid = threadIdx.x, lane = tid & 63, w = tid >> 6;
    const int q = lane >> 4, c = lane & 15;
    float2* sred = (float2*)smem;        // [32][4]
#pragma unroll
    for (int m = 0; m < 2; m++)
#pragma unroll
        for (int r = 0; r < 4; r++) {
            float s = 0.f, qq = 0.f;
#pragma unroll
            for (int j = 0; j < 8; j++) {
                float v = acc[m][j][r]; s += v; qq += v * v;
            }
            s = xr_sum16(s); qq = xr_sum16(qq);
            if (c == 0) sred[(m * 16 + q * 4 + r) * 4 + w] = make_float2(s, qq);
        }
    __syncthreads();
    float mean[2][4], rstd[2][4];
#pragma unroll
    for (int m = 0; m < 2; m++)
#pragma unroll
        for (int r = 0; r < 4; r++) {
            int row = m * 16 + q * 4 + r;
            float s = 0.f, qq = 0.f;
#pragma unroll
            for (int ww = 0; ww < 4; ww++) {
                float2 t = sred[row * 4 + ww]; s += t.x; qq += t.y;
            }
            float mn = s * (1.f / 512);
            mean[m][r] = mn;
            rstd[m][r] = rsqrtf(qq * (1.f / 512) - mn * mn + LN_EPS);
        }
    __syncthreads();
#pragma unroll
    for (int m = 0; m < 2; m++)
#pragma unroll
        for (int j = 0; j < 8; j++) {
            int col = w * 128 + j * 16 + c;
            float gv = g[col], bv = bb[col];
#pragma unroll
            for (int r = 0; r < 4; r++) {
                int row = m * 16 + q * 4 + r;
                float v = (acc[m][j][r] - mean[m][r]) * rstd[m][r] * gv + bv;
                ((__hip_bfloat16*)smem)[row * 512 + col] = __float2bfloat16(v);
            }
        }
    __syncthreads();
#pragma unroll
    for (int rnd = 0; rnd < 8; rnd++) {
        int row = rnd * 4 + w;
        uint4 v = *(const uint4*)(smem + row * 1024 + lane * 16);
        *(uint4*)((char*)out + (m0 + row) * 1024 + lane * 16) = v;
    }
}

// =============== K4: align GEMM + masked softmax ============================
__global__ __launch_bounds__(256, 2) void gemm_attn(
    const __hip_bfloat16* __restrict__ attninb,
    const __hip_bfloat16* __restrict__ pctxb,
    const int* __restrict__ mlen,
    float* __restrict__ pattn, __hip_bfloat16* __restrict__ pattnb)
{
    __shared__ char smem[32768];
    const int b = blockIdx.z;
    const long t0 = (long)blockIdx.y * 32;
    f32x4 acc[2][8];
    rows_core32(attninb + (long)b * 512 + t0 * 16384, 16384,
                pctxb + (long)b * 262144, 512, acc);

    const int tid = threadIdx.x, lane = tid & 63, w = tid >> 6;
    const int q = lane >> 4, c = lane & 15;
    const int len = mlen[b];
    float* sred = (float*)smem;          // [32][4]

#pragma unroll
    for (int m = 0; m < 2; m++)
#pragma unroll
        for (int r = 0; r < 4; r++) {
            float mx = -INFINITY;
#pragma unroll
            for (int j = 0; j < 8; j++) {
                int col = w * 128 + j * 16 + c;
                float v = acc[m][j][r] * RSQRT_D;
                acc[m][j][r] = v;
                if (col < len) mx = fmaxf(mx, v);
            }
            mx = xr_max16(mx);
            if (c == 0) sred[(m * 16 + q * 4 + r) * 4 + w] = mx;
        }
    __syncthreads();
    float rmax[2][4];
#pragma unroll
    for (int m = 0; m < 2; m++)
#pragma unroll
        for (int r = 0; r < 4; r++) {
            int row = m * 16 + q * 4 + r;
            rmax[m][r] = fmaxf(fmaxf(sred[row * 4], sred[row * 4 + 1]),
                               fmaxf(sred[row * 4 + 2], sred[row * 4 + 3]));
        }
    __syncthreads();
#pragma unroll
    for (int m = 0; m < 2; m++)
#pragma unroll
        for (int r = 0; r < 4; r++) {
            float s = 0.f;
#pragma unroll
            for (int j = 0; j < 8; j++) {
                int col = w * 128 + j * 16 + c;
                float e = (col < len) ? __expf(acc[m][j][r] - rmax[m][r]) : 0.f;
                acc[m][j][r] = e; s += e;
            }
            s = xr_sum16(s);
            if (c == 0) sred[(m * 16 + q * 4 + r) * 4 + w] = s;
        }
    __syncthreads();
    float rinv[2][4];
#pragma unroll
    for (int m = 0; m < 2; m++)
#pragma unroll
        for (int r = 0; r < 4; r++) {
            int row = m * 16 + q * 4 + r;
            rinv[m][r] = 1.f / (sred[row * 4] + sred[row * 4 + 1] +
                                sred[row * 4 + 2] + sred[row * 4 + 3]);
        }
    __syncthreads();

    // fp32 p_attn direct + bf16 repack
#pragma unroll
    for (int m = 0; m < 2; m++)
#pragma unroll
        for (int j = 0; j < 8; j++)
#pragma unroll
            for (int r = 0; r < 4; r++) {
                int row = m * 16 + q * 4 + r;
                int col = w * 128 + j * 16 + c;
                float p = acc[m][j][r] * rinv[m][r];
                acc[m][j][r] = p;
                pattn[((t0 + row) * 32 + b) * 512 + col] = p;
                ((__hip_bfloat16*)smem)[row * 512 + col] = __float2bfloat16(p);
            }
    __syncthreads();
#pragma unroll
    for (int rnd = 0; rnd < 8; rnd++) {
        int row = rnd * 4 + w;
        uint4 v = *(const uint4*)(smem + row * 1024 + lane * 16);
        *(uint4*)((char*)pattnb + ((t0 + row) * 32 + b) * 1024 + lane * 16) = v;
    }
}

// =============== K5: attn_out GEMM (scale, bf16 out) ========================
__global__ __launch_bounds__(256, 2) void gemm_av(
    const __hip_bfloat16* __restrict__ pattnb,
    const __hip_bfloat16* __restrict__ pctxT,
    __hip_bfloat16* __restrict__ attnoutb)
{
    __shared__ char smem[32768];
    const int b = blockIdx.z;
    const long t0 = (long)blockIdx.y * 32;
    f32x4 acc[2][8];
    rows_core32(pattnb + (long)b * 512 + t0 * 16384, 16384,
                pctxT + (long)b * 262144, 512, acc);

    const int tid = threadIdx.x, lane = tid & 63, w = tid >> 6;
    const int q = lane >> 4, c = lane & 15;
#pragma unroll
    for (int m = 0; m < 2; m++)
#pragma unroll
        for (int j = 0; j < 8; j++)
#pragma unroll
            for (int r = 0; r < 4; r++) {
                int row = m * 16 + q * 4 + r;
                int col = w * 128 + j * 16 + c;
                ((__hip_bfloat16*)smem)[row * 512 + col] =
                    __float2bfloat16(acc[m][j][r] * RSQRT_D);
            }
    __syncthreads();
#pragma unroll
    for (int rnd = 0; rnd < 8; rnd++) {
        int row = rnd * 4 + w;
        uint4 v = *(const uint4*)(smem + row * 1024 + lane * 16);
        *(uint4*)((char*)attnoutb + ((t0 + row) * 32 + b) * 1024 + lane * 16) = v;
    }
}

// =============== K7: h2 GEMM + LN + add t1 + tanh + highway gate ============
__global__ __launch_bounds__(256, 2) void gemm_fin(
    const __hip_bfloat16* __restrict__ attnoutb,
    const __hip_bfloat16* __restrict__ Wc,
    const __hip_bfloat16* __restrict__ h1n,
    const __hip_bfloat16* __restrict__ preb,
    const float2* __restrict__ stats,
    const float* __restrict__ g_c, const float* __restrict__ b_c,
    const float* __restrict__ g_pre, const float* __restrict__ b_pre,
    const float* __restrict__ prev, float* __restrict__ out)
{
    __shared__ char smem[65536];
    const long m0 = (long)blockIdx.y * 32;
    f32x4 acc[2][8];
    rows_core32(attnoutb + m0 * 512, 512, Wc, 512, acc);

    const int tid = threadIdx.x, lane = tid & 63, w = tid >> 6;
    const int q = lane >> 4, c = lane & 15;
    float2* sred = (float2*)smem;        // [32][4]
#pragma unroll
    for (int m = 0; m < 2; m++)
#pragma unroll
        for (int r = 0; r < 4; r++) {
            float s = 0.f, qq = 0.f;
#pragma unroll
            for (int j = 0; j < 8; j++) {
                float v = acc[m][j][r]; s += v; qq += v * v;
            }
            s = xr_sum16(s); qq = xr_sum16(qq);
            if (c == 0) sred[(m * 16 + q * 4 + r) * 4 + w] = make_float2(s, qq);
        }
    __syncthreads();
    float mean[2][4], rstd[2][4];
#pragma unroll
    for (int m = 0; m < 2; m++)
#pragma unroll
        for (int r = 0; r < 4; r++) {
            int row = m * 16 + q * 4 + r;
            float s = 0.f, qq = 0.f;
#pragma unroll
            for (int ww = 0; ww < 4; ww++) {
                float2 t = sred[row * 4 + ww]; s += t.x; qq += t.y;
            }
            float mn = s * (1.f / 512);
            mean[m][r] = mn;
            rstd[m][r] = rsqrtf(qq * (1.f / 512) - mn * mn + LN_EPS);
        }
    __syncthreads();

    // ---- t2 = LN(h2) -> f32 LDS [32][512] (64KB) ----
    float* t2s = (float*)smem;
#pragma unroll
    for (int m = 0; m < 2; m++)
#pragma unroll
        for (int j = 0; j < 8; j++) {
            int col = w * 128 + j * 16 + c;
            float gv = g_c[col], bv = b_c[col];
#pragma unroll
            for (int r = 0; r < 4; r++) {
                int row = m * 16 + q * 4 + r;
                t2s[row * 512 + col] =
                    (acc[m][j][r] - mean[m][r]) * rstd[m][r] * gv + bv;
            }
        }
    __syncthreads();

    // ---- vectorized fused pass: 4096 float4s, fully coalesced ----
#pragma unroll
    for (int ch = 0; ch < 16; ch++) {
        int f4 = ch * 256 + tid;             // 0..4095
        int row = f4 >> 7;                   // local row (2 rows per chunk)
        long rowg = m0 + row;
        int col = (f4 & 127) * 4;
        float4 t2 = ((const float4*)t2s)[f4];
        ushort4 h1 = *(const ushort4*)((const char*)h1n + rowg * 1024 + col * 2);
        ushort4 hr = *(const ushort4*)((const char*)preb + rowg * 3072 + 1024 + col * 2);
        float4 pv = *(const float4*)(prev + rowg * 512 + col);
        float4 gp = *(const float4*)(g_pre + 512 + col);
        float4 bp = *(const float4*)(b_pre + 512 + col);
        float2 sh = stats[rowg];
        auto fuse = [&](unsigned short h1u, unsigned short hru, float t2v,
                        float pvv, float gpv, float bpv) -> float {
            float hg = sigmoid_fast((bfu(hru) - sh.x) * sh.y * gpv + bpv);
            float th = tanh_fast(bfu(h1u) + t2v);
            return (1.f - hg) * th + hg * pvv;
        };
        float4 o;
        o.x = fuse(h1.x, hr.x, t2.x, pv.x, gp.x, bp.x);
        o.y = fuse(h1.y, hr.y, t2.y, pv.y, gp.y, bp.y);
        o.z = fuse(h1.z, hr.z, t2.z, pv.z, gp.z, bp.z);
        o.w = fuse(h1.w, hr.w, t2.w, pv.w, gp.w, bp.w);
        *(float4*)(out + rowg * 512 + col) = o;
    }
}

// =============== small kernels ==============================================
__global__ __launch_bounds__(256) void cvt4(
    const float* __restrict__ x, __hip_bfloat16* __restrict__ y, int n4)
{
    int i = blockIdx.x * 256 + threadIdx.x;
    if (i >= n4) return;
    float4 v = ((const float4*)x)[i];
    bfx4 o;
    o.x = __float2bfloat16(v.x); o.y = __float2bfloat16(v.y);
    o.z = __float2bfloat16(v.z); o.w = __float2bfloat16(v.w);
    ((bfx4*)y)[i] = o;
}

__global__ __launch_bounds__(256) void wtrans(
    const float* __restrict__ w0, const float* __restrict__ w1,
    const float* __restrict__ w2, const float* __restrict__ w3,
    const float* __restrict__ w4, __hip_bfloat16* __restrict__ WT)
{
    int z = blockIdx.z;
    const float* W; long off; int N;
    if (z == 0)      { W = w0; off = 0;                N = 1536; }
    else if (z == 1) { W = w1; off = 786432;           N = 512; }
    else if (z == 2) { W = w2; off = 786432 + 262144;  N = 512; }
    else if (z == 3) { W = w3; off = 786432 + 524288;  N = 512; }
    else             { W = w4; off = 786432 + 786432;  N = 512; }
    int n0 = blockIdx.x * 32, k0 = blockIdx.y * 32;
    if (n0 >= N) return;
    __shared__ float t[32][33];
    int tx = threadIdx.x & 31, ty = threadIdx.x >> 5;
#pragma unroll
    for (int i = 0; i < 4; i++)
        t[ty + i * 8][tx] = W[(long)(k0 + ty + i * 8) * N + n0 + tx];
    __syncthreads();
    __hip_bfloat16* O = WT + off;
#pragma unroll
    for (int i = 0; i < 4; i++)
        O[(long)(n0 + ty + i * 8) * 512 + k0 + tx] =
            __float2bfloat16(t[tx][ty + i * 8]);
}

__global__ __launch_bounds__(256) void ptrans(
    const __hip_bfloat16* __restrict__ src, __hip_bfloat16* __restrict__ dst)
{
    long boff = (long)blockIdx.z * (S_ * D_);
    int d0 = blockIdx.x * 32, s0 = blockIdx.y * 32;
    __shared__ __hip_bfloat16 t[32][34];
    int tx = threadIdx.x & 31, ty = threadIdx.x >> 5;
#pragma unroll
    for (int i = 0; i < 4; i++)
        t[ty + i * 8][tx] = src[boff + (long)(s0 + ty + i * 8) * D_ + d0 + tx];
    __syncthreads();
#pragma unroll
    for (int i = 0; i < 4; i++)
        dst[boff + (long)(d0 + ty + i * 8) * S_ + s0 + tx] = t[tx][ty + i * 8];
}

__global__ __launch_bounds__(256) void stats_fin(
    const float2* __restrict__ part, float2* __restrict__ stats)
{
    int r = blockIdx.x * 256 + threadIdx.x;
    float s = 0.f, qq = 0.f;
#pragma unroll
    for (int cb = 0; cb < 12; cb++) {
        float2 v = part[(long)cb * 16384 + r]; s += v.x; qq += v.y;
    }
    float m = s * (1.f / 1536);
    float rs = rsqrtf(qq * (1.f / 1536) - m * m + LN_EPS);
    stats[r] = make_float2(m, rs);
}

// ---------------- chunked SRU scan with inline LN ---------------------------
__global__ __launch_bounds__(256) void scan_part1(
    const __hip_bfloat16* __restrict__ preb, const float2* __restrict__ stats,
    const float* __restrict__ gpre, const float* __restrict__ bpre,
    float* __restrict__ Ap, float* __restrict__ Bp)
{
    int idx = blockIdx.x * 256 + threadIdx.x;   // b*512+d
    int b = idx >> 9, d = idx & 511;
    int ch = blockIdx.y;
    float gz = gpre[d], bz = bpre[d];
    float gp = gpre[1024 + d], bpv = bpre[1024 + d];
    float A = 1.f, s = 0.f;
    for (int t = ch * CT; t < (ch + 1) * CT; t++) {
        long row = (long)t * 32 + b;
        float2 st = stats[row];
        float zr = __bfloat162float(preb[row * 1536 + d]);
        float pr = __bfloat162float(preb[row * 1536 + 1024 + d]);
        float z = sigmoidf_((zr - st.x) * st.y * gz + bz);
        float pl = (pr - st.x) * st.y * gp + bpv;
        float a = 1.f - z;
        A *= a;
        s = a * s + z * pl;
    }
    Ap[ch * 16384 + idx] = A;
    Bp[ch * 16384 + idx] = s;
}

__global__ __launch_bounds__(256) void scan_part2(
    const float* __restrict__ Ap, const float* __restrict__ Bp,
    const float* __restrict__ h0, float* __restrict__ sin_,
    float* __restrict__ hlast)
{
    int idx = blockIdx.x * 256 + threadIdx.x;
    float s = h0[idx];
    for (int ch = 0; ch < NCH; ch++) {
        sin_[ch * 16384 + idx] = s;
        s = Ap[ch * 16384 + idx] * s + Bp[ch * 16384 + idx];
    }
    hlast[idx] = s;
}

__global__ __launch_bounds__(256) void scan_part3(
    const __hip_bfloat16* __restrict__ preb, const float2* __restrict__ stats,
    const float* __restrict__ gpre, const float* __restrict__ bpre,
    const float* __restrict__ sin_, __hip_bfloat16* __restrict__ ssb)
{
    int idx = blockIdx.x * 256 + threadIdx.x;
    int b = idx >> 9, d = idx & 511;
    int ch = blockIdx.y;
    float gz = gpre[d], bz = bpre[d];
    float gp = gpre[1024 + d], bpv = bpre[1024 + d];
    float s = sin_[ch * 16384 + idx];
    for (int t = ch * CT; t < (ch + 1) * CT; t++) {
        long row = (long)t * 32 + b;
        float2 st = stats[row];
        float zr = __bfloat162float(preb[row * 1536 + d]);
        float pr = __bfloat162float(preb[row * 1536 + 1024 + d]);
        float z = sigmoidf_((zr - st.x) * st.y * gz + bz);
        float pl = (pr - st.x) * st.y * gp + bpv;
        s += z * (pl - s);
        ssb[(long)t * 16384 + idx] = __float2bfloat16(s);
    }
}

extern "C" void kernel_launch(void* const* d_in, const int* in_sizes, int n_in,
                              void* d_out, int out_size, void* d_ws, size_t ws_size,
                              hipStream_t stream) {
    const float* prev  = (const float*)d_in[0];
    const float* hid0  = (const float*)d_in[1];
    const float* enc   = (const float*)d_in[2];
    const int*   mlen  = (const int*)  d_in[3];
    const float* W_in  = (const float*)d_in[4];
    const float* W_enc = (const float*)d_in[5];
    const float* W_att = (const float*)d_in[6];
    const float* W_hid = (const float*)d_in[7];
    const float* W_ctx = (const float*)d_in[8];
    const float* g_pre = (const float*)d_in[9];
    const float* b_pre = (const float*)d_in[10];
    const float* g_enc = (const float*)d_in[11];
    const float* b_enc = (const float*)d_in[12];
    const float* g_att = (const float*)d_in[13];
    const float* b_att = (const float*)d_in[14];
    const float* g_h   = (const float*)d_in[15];
    const float* b_h   = (const float*)d_in[16];
    const float* g_c   = (const float*)d_in[17];
    const float* b_c   = (const float*)d_in[18];

    float* out   = (float*)d_out;                 // [T,B,D]
    float* hlast = out + (long)T_ * B_ * D_;      // [B,D]
    float* pattn = hlast + (long)B_ * D_;         // [T,B,S]

    char* ws = (char*)d_ws;
    __hip_bfloat16* preb    = (__hip_bfloat16*)(ws);               // 48MB
    __hip_bfloat16* WT      = (__hip_bfloat16*)(ws + 50331648);    // 4MB
    __hip_bfloat16* prevb   = (__hip_bfloat16*)(ws + 54525952);    // 16MB
    __hip_bfloat16* encb    = (__hip_bfloat16*)(ws + 71303168);    // 16MB
    __hip_bfloat16* pctxb   = (__hip_bfloat16*)(ws + 88080384);    // 16MB
    __hip_bfloat16* pctxT   = (__hip_bfloat16*)(ws + 104857600);   // 16MB
    __hip_bfloat16* ssb     = (__hip_bfloat16*)(ws + 121634816);   // 16MB
    __hip_bfloat16* attninb = (__hip_bfloat16*)(ws + 138412032);   // 16MB
    __hip_bfloat16* pattnb  = (__hip_bfloat16*)(ws + 155189248);   // 16MB
    __hip_bfloat16* attnoutb= (__hip_bfloat16*)(ws + 171966464);   // 16MB
    __hip_bfloat16* h1n     = (__hip_bfloat16*)(ws + 188743680);   // 16MB
    float2* part            = (float2*)(ws + 205520896);           // 1.5MB
    float2* stats           = (float2*)(ws + 207093760);           // 128KB
    // scan buffers: each [NCH][16384] floats = 1 MB
    float* scanA            = (float*)(ws + 207224832);
    float* scanB            = (float*)(ws + 208273408);
    float* sinb             = (float*)(ws + 209321984);

    const __hip_bfloat16* W_encT = WT + 786432;
    const __hip_bfloat16* W_attT = WT + 786432 + 262144;
    const __hip_bfloat16* W_hidT = WT + 786432 + 524288;
    const __hip_bfloat16* W_ctxT = WT + 786432 + 786432;

    dim3 blk(256);

    // inputs -> bf16
    cvt4<<<8192, blk, 0, stream>>>(prev, prevb, 2097152);
    cvt4<<<8192, blk, 0, stream>>>(enc, encb, 2097152);
    wtrans<<<dim3(48, 16, 5), blk, 0, stream>>>(W_in, W_enc, W_att, W_hid,
                                                W_ctx, WT);

    // K1: preact GEMM -> preb bf16 + LN partials
    gemm_pre<<<dim3(12, 128), blk, 0, stream>>>(prevb, WT, preb, part);
    stats_fin<<<64, blk, 0, stream>>>(part, stats);

    // SRU scan (inline LN on preb)
    scan_part1<<<dim3(64, NCH), blk, 0, stream>>>(preb, stats, g_pre, b_pre,
                                                  scanA, scanB);
    scan_part2<<<64, blk, 0, stream>>>(scanA, scanB, hid0, sinb, hlast);
    scan_part3<<<dim3(64, NCH), blk, 0, stream>>>(preb, stats, g_pre, b_pre,
                                                  sinb, ssb);

    // K2: pctx = LN(enc @ W_enc) -> bf16 (+ transposed copy)
    gemm_ln<<<dim3(1, 512), blk, 0, stream>>>(encb, 512, W_encT, g_enc, b_enc,
                                              pctxb);
    ptrans<<<dim3(16, 16, 32), blk, 0, stream>>>(pctxb, pctxT);

    // K3: attn_in = LN(ss @ W_attn_in) -> bf16
    gemm_ln<<<dim3(1, 512), blk, 0, stream>>>(ssb, 512, W_attT, g_att, b_att,
                                              attninb);

    // K4: align + masked softmax -> pattn fp32 + pattnb bf16
    gemm_attn<<<dim3(1, 16, 32), blk, 0, stream>>>(attninb, pctxb, mlen,
                                                   pattn, pattnb);

    // K5: attn_out = av @ pctx / sqrt(d) -> bf16
    gemm_av<<<dim3(1, 16, 32), blk, 0, stream>>>(pattnb, pctxT, attnoutb);

    // K6: h1n = LN(ss @ W_hidden) -> bf16
    gemm_ln<<<dim3(1, 512), blk, 0, stream>>>(ssb, 512, W_hidT, g_h, b_h, h1n);

    // K7: out = (1-hg)*tanh(h1n + LN(attn_out @ W_ctx)) + hg*prev
    gemm_fin<<<dim3(1, 512), blk, 0, stream>>>(attnoutb, W_ctxT, h1n, preb,
                                               stats, g_c, b_c, g_pre, b_pre,
                                               prev, out);
}

// Round 4
// 448.508 us; speedup vs baseline: 1.1673x; 1.1673x over previous
//
#include <hip/hip_runtime.h>
#include <hip/hip_bf16.h>
#include <cmath>

#define T_ 512
#define B_ 32
#define S_ 512
#define D_ 512
#define D3_ 1536
#define NCH 16
#define CT (T_ / NCH)
static constexpr float LN_EPS = 1e-6f;
static constexpr float RSQRT_D = 0.044194173824159216f; // 1/sqrt(512)

typedef __attribute__((ext_vector_type(8))) __bf16 bf16x8;
typedef __attribute__((ext_vector_type(4))) float f32x4;

struct __align__(8) bfx4 { __hip_bfloat16 x, y, z, w; };
struct __align__(16) u16x8 { unsigned short h[8]; };

// ---------------- async global->LDS, 16B per lane ---------------------------
__device__ __forceinline__ void g2l16(const void* g, void* l) {
    __builtin_amdgcn_global_load_lds(
        (const __attribute__((address_space(1))) unsigned int*)g,
        (__attribute__((address_space(3))) unsigned int*)l, 16, 0, 0);
}

// 16-lane xor reductions
__device__ __forceinline__ float xr_sum16(float v) {
    v += __shfl_xor(v, 1); v += __shfl_xor(v, 2);
    v += __shfl_xor(v, 4); v += __shfl_xor(v, 8); return v;
}
__device__ __forceinline__ float xr_max16(float v) {
    v = fmaxf(v, __shfl_xor(v, 1)); v = fmaxf(v, __shfl_xor(v, 2));
    v = fmaxf(v, __shfl_xor(v, 4)); v = fmaxf(v, __shfl_xor(v, 8)); return v;
}

__device__ __forceinline__ float sigmoidf_(float x) {
    return 1.f / (1.f + __expf(-x));
}
__device__ __forceinline__ float sigmoid_fast(float x) {
    return __fdividef(1.f, 1.f + __expf(-x));
}
__device__ __forceinline__ float tanh_fast(float x) {
    return 1.f - __fdividef(2.f, __expf(2.f * x) + 1.f);
}
__device__ __forceinline__ float bfu(unsigned short u) {
    unsigned int v = ((unsigned int)u) << 16;
    return __uint_as_float(v);
}

// =============== K1: preact GEMM 128x128, double-buffered ===================
__global__ __launch_bounds__(256) void gemm_pre(
    const __hip_bfloat16* __restrict__ A,
    const __hip_bfloat16* __restrict__ Bw,
    __hip_bfloat16* __restrict__ preb,
    float2* __restrict__ part)
{
    __shared__ char smem[32768];   // 2 x (A 8KB | B 8KB)

    const int lin = blockIdx.y * 12 + blockIdx.x;       // dispatch order
    const int swz = (lin & 7) * 192 + (lin >> 3);       // XCD-contiguous
    const int bx = swz % 12, by = swz / 12;
    const int m0 = by * 128, n0 = bx * 128;
    const int tid = threadIdx.x, lane = tid & 63, w = tid >> 6;
    const int wm = (w >> 1) * 64, wn = (w & 1) * 64;
    const int srow = lane >> 2, skB = (lane & 3) * 16;
    const int q = lane >> 4, c = lane & 15;

    f32x4 acc[4][4];
#pragma unroll
    for (int i = 0; i < 4; i++)
#pragma unroll
        for (int j = 0; j < 4; j++) acc[i][j] = (f32x4)(0.0f);

    const char* ga0 = (const char*)(A + (long)(m0 + w * 16 + srow) * 512) + skB;
    const char* ga1 = (const char*)(A + (long)(m0 + (w + 4) * 16 + srow) * 512) + skB;
    const char* gb0 = (const char*)(Bw + (long)(n0 + w * 16 + srow) * 512) + skB;
    const char* gb1 = (const char*)(Bw + (long)(n0 + (w + 4) * 16 + srow) * 512) + skB;
    char* la0 = smem + w * 1024 + lane * 16;
    char* la1 = smem + (w + 4) * 1024 + lane * 16;
    char* lb0 = smem + 8192 + w * 1024 + lane * 16;
    char* lb1 = smem + 8192 + (w + 4) * 1024 + lane * 16;
    const char* Ar = smem + (wm + c) * 64 + q * 16;
    const char* Br = smem + 8192 + (wn + c) * 64 + q * 16;

    g2l16(ga0, la0);
    g2l16(ga1, la1);
    g2l16(gb0, lb0);
    g2l16(gb1, lb1);
    __syncthreads();

#pragma unroll
    for (int kk = 0; kk < 16; kk++) {
        const int cb = (kk & 1) << 14;
        const int nb = cb ^ 16384;
        if (kk < 15) {
            const long kb = (long)(kk + 1) * 64;
            g2l16(ga0 + kb, la0 + nb);
            g2l16(ga1 + kb, la1 + nb);
            g2l16(gb0 + kb, lb0 + nb);
            g2l16(gb1 + kb, lb1 + nb);
        }
        bf16x8 af[4], bfr[4];
#pragma unroll
        for (int i = 0; i < 4; i++) {
            af[i] = *(const bf16x8*)(Ar + cb + i * 1024);
            bfr[i] = *(const bf16x8*)(Br + cb + i * 1024);
        }
#pragma unroll
        for (int i = 0; i < 4; i++)
#pragma unroll
            for (int j = 0; j < 4; j++)
                acc[i][j] = __builtin_amdgcn_mfma_f32_16x16x32_bf16(
                    af[i], bfr[j], acc[i][j], 0, 0, 0);
        __syncthreads();
    }

    float2* sred = (float2*)smem;        // [128][2]
#pragma unroll
    for (int i = 0; i < 4; i++)
#pragma unroll
        for (int r = 0; r < 4; r++) {
            float s = 0.f, qq = 0.f;
#pragma unroll
            for (int j = 0; j < 4; j++) {
                float v = acc[i][j][r]; s += v; qq += v * v;
            }
            s = xr_sum16(s); qq = xr_sum16(qq);
            if (c == 0) sred[(wm + i * 16 + q * 4 + r) * 2 + (w & 1)] =
                make_float2(s, qq);
        }
    __syncthreads();
    if ((w & 1) == 0 && c == 0) {
#pragma unroll
        for (int i = 0; i < 4; i++)
#pragma unroll
            for (int r = 0; r < 4; r++) {
                int row = wm + i * 16 + q * 4 + r;
                float2 a = sred[row * 2], b2 = sred[row * 2 + 1];
                part[(long)bx * 16384 + m0 + row] =
                    make_float2(a.x + b2.x, a.y + b2.y);
            }
    }
    __syncthreads();

    for (int p = 0; p < 2; p++) {
        if ((w >> 1) == p) {
#pragma unroll
            for (int i = 0; i < 4; i++)
#pragma unroll
                for (int j = 0; j < 4; j++)
#pragma unroll
                    for (int r = 0; r < 4; r++) {
                        int row = i * 16 + q * 4 + r;
                        int col = wn + j * 16 + c;
                        ((__hip_bfloat16*)smem)[row * 128 + col] =
                            __float2bfloat16(acc[i][j][r]);
                    }
        }
        __syncthreads();
#pragma unroll
        for (int rnd = 0; rnd < 4; rnd++) {
            int row = rnd * 16 + (tid >> 4);
            int ch = tid & 15;
            uint4 v = *(const uint4*)(smem + row * 256 + ch * 16);
            long grow = m0 + p * 64 + row;
            *(uint4*)((char*)preb + grow * 3072 + (long)n0 * 2 + ch * 16) = v;
        }
        __syncthreads();
    }
}

// =============== generic 128x128 GEMM (m97 structure), N=512 ================
// A [M,ldaE] bf16 k-major rows; B = weight-like [512 n-rows, 512 k] bf16.
// Writes bf16(acc*scale) into out rows with byte stride outStrideB, and
// optional per-block row (sum,sumsq) partials (for downstream LayerNorm).
// z-grid > 1 => per-batch operand offsets (A += z*512 elems, B += z*bStrideZ,
// out += z*512 elems). XCD swizzle only for z==1 grids (nwg % 8 == 0).
__global__ __launch_bounds__(256) void g128(
    const __hip_bfloat16* __restrict__ A, long ldaE,
    const __hip_bfloat16* __restrict__ Bw, long bStrideZ,
    __hip_bfloat16* __restrict__ out, long outStrideB,
    float2* __restrict__ part, float scale, int swizzle)
{
    __shared__ char smem[32768];
    int bx, by;
    if (gridDim.z > 1) {
        bx = blockIdx.x; by = blockIdx.y;
        A += (long)blockIdx.z * 512;
        Bw += (long)blockIdx.z * bStrideZ;
        out += (long)blockIdx.z * 512;
    } else if (swizzle) {
        const int nwg = gridDim.x * gridDim.y;
        const int lin = blockIdx.y * gridDim.x + blockIdx.x;
        const int cpx = nwg >> 3;
        const int swz = (lin & 7) * cpx + (lin >> 3);
        bx = swz % gridDim.x; by = swz / gridDim.x;
    } else { bx = blockIdx.x; by = blockIdx.y; }

    const int m0 = by * 128, n0 = bx * 128;
    const int tid = threadIdx.x, lane = tid & 63, w = tid >> 6;
    const int wm = (w >> 1) * 64, wn = (w & 1) * 64;
    const int srow = lane >> 2, skB = (lane & 3) * 16;
    const int q = lane >> 4, c = lane & 15;

    f32x4 acc[4][4];
#pragma unroll
    for (int i = 0; i < 4; i++)
#pragma unroll
        for (int j = 0; j < 4; j++) acc[i][j] = (f32x4)(0.0f);

    const char* ga0 = (const char*)(A + (long)(m0 + w * 16 + srow) * ldaE) + skB;
    const char* ga1 = (const char*)(A + (long)(m0 + (w + 4) * 16 + srow) * ldaE) + skB;
    const char* gb0 = (const char*)(Bw + (long)(n0 + w * 16 + srow) * 512) + skB;
    const char* gb1 = (const char*)(Bw + (long)(n0 + (w + 4) * 16 + srow) * 512) + skB;
    char* la0 = smem + w * 1024 + lane * 16;
    char* la1 = smem + (w + 4) * 1024 + lane * 16;
    char* lb0 = smem + 8192 + w * 1024 + lane * 16;
    char* lb1 = smem + 8192 + (w + 4) * 1024 + lane * 16;
    const char* Ar = smem + (wm + c) * 64 + q * 16;
    const char* Br = smem + 8192 + (wn + c) * 64 + q * 16;

    g2l16(ga0, la0);
    g2l16(ga1, la1);
    g2l16(gb0, lb0);
    g2l16(gb1, lb1);
    __syncthreads();

#pragma unroll
    for (int kk = 0; kk < 16; kk++) {
        const int cb = (kk & 1) << 14;
        const int nb = cb ^ 16384;
        if (kk < 15) {
            const long kb = (long)(kk + 1) * 64;
            g2l16(ga0 + kb, la0 + nb);
            g2l16(ga1 + kb, la1 + nb);
            g2l16(gb0 + kb, lb0 + nb);
            g2l16(gb1 + kb, lb1 + nb);
        }
        bf16x8 af[4], bfr[4];
#pragma unroll
        for (int i = 0; i < 4; i++) {
            af[i] = *(const bf16x8*)(Ar + cb + i * 1024);
            bfr[i] = *(const bf16x8*)(Br + cb + i * 1024);
        }
#pragma unroll
        for (int i = 0; i < 4; i++)
#pragma unroll
            for (int j = 0; j < 4; j++)
                acc[i][j] = __builtin_amdgcn_mfma_f32_16x16x32_bf16(
                    af[i], bfr[j], acc[i][j], 0, 0, 0);
        __syncthreads();
    }

    // ---- optional row-stat partials over this block's 128 cols ----
    if (part) {
        float2* sred = (float2*)smem;    // [128][2]
#pragma unroll
        for (int i = 0; i < 4; i++)
#pragma unroll
            for (int r = 0; r < 4; r++) {
                float s = 0.f, qq = 0.f;
#pragma unroll
                for (int j = 0; j < 4; j++) {
                    float v = acc[i][j][r]; s += v; qq += v * v;
                }
                s = xr_sum16(s); qq = xr_sum16(qq);
                if (c == 0) sred[(wm + i * 16 + q * 4 + r) * 2 + (w & 1)] =
                    make_float2(s, qq);
            }
        __syncthreads();
        if ((w & 1) == 0 && c == 0) {
#pragma unroll
            for (int i = 0; i < 4; i++)
#pragma unroll
                for (int r = 0; r < 4; r++) {
                    int row = wm + i * 16 + q * 4 + r;
                    float2 a = sred[row * 2], b2 = sred[row * 2 + 1];
                    part[(long)bx * 16384 + m0 + row] =
                        make_float2(a.x + b2.x, a.y + b2.y);
                }
        }
        __syncthreads();
    }

    // ---- bf16(acc*scale) store via LDS repack ----
    for (int p = 0; p < 2; p++) {
        if ((w >> 1) == p) {
#pragma unroll
            for (int i = 0; i < 4; i++)
#pragma unroll
                for (int j = 0; j < 4; j++)
#pragma unroll
                    for (int r = 0; r < 4; r++) {
                        int row = i * 16 + q * 4 + r;
                        int col = wn + j * 16 + c;
                        ((__hip_bfloat16*)smem)[row * 128 + col] =
                            __float2bfloat16(acc[i][j][r] * scale);
                    }
        }
        __syncthreads();
#pragma unroll
        for (int rnd = 0; rnd < 4; rnd++) {
            int row = rnd * 16 + (tid >> 4);
            int ch = tid & 15;
            uint4 v = *(const uint4*)(smem + row * 256 + ch * 16);
            long grow = m0 + p * 64 + row;
            *(uint4*)((char*)out + grow * outStrideB + (long)n0 * 2 + ch * 16) = v;
        }
        __syncthreads();
    }
}

// =============== K4 core: 32 rows x full N=512, LDS double-buffered =========
#define RC_BUF 34816
__device__ __forceinline__ void rows_core32_lds(
    const __hip_bfloat16* A, long lda,
    const __hip_bfloat16* B, long ldb,
    char* smem, f32x4 (&acc)[2][8])
{
    const int tid = threadIdx.x, lane = tid & 63, w = tid >> 6;
#pragma unroll
    for (int m = 0; m < 2; m++)
#pragma unroll
        for (int j = 0; j < 8; j++) acc[m][j] = (f32x4)(0.0f);

    const char* ga = (const char*)(A + (long)(w * 16 + (lane >> 2)) * lda) + (lane & 3) * 16;
    char* la = smem + w * 1024 + lane * 16;
    const char* gb = (const char*)(B + (long)(w * 128 + (lane >> 2)) * ldb) + (lane & 3) * 16;
    char* lb = smem + 2048 + w * 8192 + lane * 16;
    const long ldbB16 = (long)ldb * 32;
    const char* Ar = smem + (lane & 15) * 64 + (lane >> 4) * 16;
    const char* Br = smem + 2048 + (w * 128 + (lane & 15)) * 64 + (lane >> 4) * 16;

    if (w < 2) g2l16(ga, la);
#pragma unroll
    for (int s = 0; s < 8; s++) g2l16(gb + s * ldbB16, lb + s * 1024);
    __syncthreads();

#pragma unroll
    for (int kk = 0; kk < 16; kk++) {
        const int cb = (kk & 1) * RC_BUF;
        const int nb = ((kk & 1) ^ 1) * RC_BUF;
        if (kk < 15) {
            const long kb = (long)(kk + 1) * 64;
            if (w < 2) g2l16(ga + kb, la + nb);
#pragma unroll
            for (int s = 0; s < 8; s++)
                g2l16(gb + kb + s * ldbB16, lb + nb + s * 1024);
        }
        bf16x8 af[2], bfr[8];
#pragma unroll
        for (int m = 0; m < 2; m++) af[m] = *(const bf16x8*)(Ar + cb + m * 1024);
#pragma unroll
        for (int j = 0; j < 8; j++) bfr[j] = *(const bf16x8*)(Br + cb + j * 1024);
#pragma unroll
        for (int m = 0; m < 2; m++)
#pragma unroll
            for (int j = 0; j < 8; j++)
                acc[m][j] = __builtin_amdgcn_mfma_f32_16x16x32_bf16(
                    af[m], bfr[j], acc[m][j], 0, 0, 0);
        __syncthreads();
    }
}

// =============== K4: align GEMM + masked softmax ============================
__global__ __launch_bounds__(256, 2) void gemm_attn(
    const __hip_bfloat16* __restrict__ attninb,
    const __hip_bfloat16* __restrict__ pctxb,
    const int* __restrict__ mlen,
    float* __restrict__ pattn, __hip_bfloat16* __restrict__ pattnb)
{
    __shared__ char smem[69632];
    const int b = blockIdx.z;
    const long t0 = (long)blockIdx.y * 32;
    f32x4 acc[2][8];
    rows_core32_lds(attninb + (long)b * 512 + t0 * 16384, 16384,
                    pctxb + (long)b * 262144, 512, smem, acc);

    const int tid = threadIdx.x, lane = tid & 63, w = tid >> 6;
    const int q = lane >> 4, c = lane & 15;
    const int len = mlen[b];
    float* sred = (float*)smem;          // [32][4]

#pragma unroll
    for (int m = 0; m < 2; m++)
#pragma unroll
        for (int r = 0; r < 4; r++) {
            float mx = -INFINITY;
#pragma unroll
            for (int j = 0; j < 8; j++) {
                int col = w * 128 + j * 16 + c;
                float v = acc[m][j][r] * RSQRT_D;
                acc[m][j][r] = v;
                if (col < len) mx = fmaxf(mx, v);
            }
            mx = xr_max16(mx);
            if (c == 0) sred[(m * 16 + q * 4 + r) * 4 + w] = mx;
        }
    __syncthreads();
    float rmax[2][4];
#pragma unroll
    for (int m = 0; m < 2; m++)
#pragma unroll
        for (int r = 0; r < 4; r++) {
            int row = m * 16 + q * 4 + r;
            rmax[m][r] = fmaxf(fmaxf(sred[row * 4], sred[row * 4 + 1]),
                               fmaxf(sred[row * 4 + 2], sred[row * 4 + 3]));
        }
    __syncthreads();
#pragma unroll
    for (int m = 0; m < 2; m++)
#pragma unroll
        for (int r = 0; r < 4; r++) {
            float s = 0.f;
#pragma unroll
            for (int j = 0; j < 8; j++) {
                int col = w * 128 + j * 16 + c;
                float e = (col < len) ? __expf(acc[m][j][r] - rmax[m][r]) : 0.f;
                acc[m][j][r] = e; s += e;
            }
            s = xr_sum16(s);
            if (c == 0) sred[(m * 16 + q * 4 + r) * 4 + w] = s;
        }
    __syncthreads();
    float rinv[2][4];
#pragma unroll
    for (int m = 0; m < 2; m++)
#pragma unroll
        for (int r = 0; r < 4; r++) {
            int row = m * 16 + q * 4 + r;
            rinv[m][r] = 1.f / (sred[row * 4] + sred[row * 4 + 1] +
                                sred[row * 4 + 2] + sred[row * 4 + 3]);
        }
    __syncthreads();

#pragma unroll
    for (int m = 0; m < 2; m++)
#pragma unroll
        for (int j = 0; j < 8; j++)
#pragma unroll
            for (int r = 0; r < 4; r++) {
                int row = m * 16 + q * 4 + r;
                int col = w * 128 + j * 16 + c;
                float p = acc[m][j][r] * rinv[m][r];
                acc[m][j][r] = p;
                pattn[((t0 + row) * 32 + b) * 512 + col] = p;
                ((__hip_bfloat16*)smem)[row * 512 + col] = __float2bfloat16(p);
            }
    __syncthreads();
#pragma unroll
    for (int rnd = 0; rnd < 8; rnd++) {
        int row = rnd * 4 + w;
        uint4 v = *(const uint4*)(smem + row * 1024 + lane * 16);
        *(uint4*)((char*)pattnb + ((t0 + row) * 32 + b) * 1024 + lane * 16) = v;
    }
}

// =============== stats reduce (4 partial panels, N=512) =====================
__global__ __launch_bounds__(256) void stats4(
    const float2* __restrict__ part, float2* __restrict__ st)
{
    int r = blockIdx.x * 256 + threadIdx.x;
    float s = 0.f, qq = 0.f;
#pragma unroll
    for (int cb = 0; cb < 4; cb++) {
        float2 v = part[(long)cb * 16384 + r]; s += v.x; qq += v.y;
    }
    float m = s * (1.f / 512);
    float rs = rsqrtf(qq * (1.f / 512) - m * m + LN_EPS);
    st[r] = make_float2(m, rs);
}

// =============== in-place LayerNorm apply (bf16, stats-based) ===============
__global__ __launch_bounds__(256) void ln_apply(
    __hip_bfloat16* __restrict__ x, const float2* __restrict__ st,
    const float* __restrict__ g, const float* __restrict__ bb)
{
    int i = blockIdx.x * 256 + threadIdx.x;   // uint4 index (8 bf16), 1M total
    int row = i >> 6;
    int c0 = (i & 63) * 8;
    float2 s = st[row];
    u16x8 v = *(const u16x8*)((const char*)x + (long)i * 16);
    float4 g0 = *(const float4*)(g + c0), g1 = *(const float4*)(g + c0 + 4);
    float4 b0 = *(const float4*)(bb + c0), b1 = *(const float4*)(bb + c0 + 4);
    float gv[8] = {g0.x, g0.y, g0.z, g0.w, g1.x, g1.y, g1.z, g1.w};
    float bv[8] = {b0.x, b0.y, b0.z, b0.w, b1.x, b1.y, b1.z, b1.w};
#pragma unroll
    for (int k = 0; k < 8; k++) {
        float f = (bfu(v.h[k]) - s.x) * s.y * gv[k] + bv[k];
        v.h[k] = __hip_bfloat16_raw(__float2bfloat16(f)).x;
    }
    *(u16x8*)((char*)x + (long)i * 16) = v;
}

// =============== final elementwise fuse =====================================
// out = (1-hg)*tanh(LN_h(h1raw) + LN_c(h2raw)) + hg*prev
// hg = sigmoid(LN_pre(preb hslice))
__global__ __launch_bounds__(256) void fin_ep(
    const __hip_bfloat16* __restrict__ h2r, const __hip_bfloat16* __restrict__ h1r,
    const __hip_bfloat16* __restrict__ preb,
    const float2* __restrict__ st_c, const float2* __restrict__ st_h,
    const float2* __restrict__ st_p,
    const float* __restrict__ g_c, const float* __restrict__ b_c,
    const float* __restrict__ g_h, const float* __restrict__ b_h,
    const float* __restrict__ g_pre, const float* __restrict__ b_pre,
    const float* __restrict__ prev, float* __restrict__ out)
{
    const long m0 = (long)blockIdx.x * 32;
    const int tid = threadIdx.x;
#pragma unroll
    for (int ch = 0; ch < 16; ch++) {
        int f4 = ch * 256 + tid;             // 0..4095
        int row = f4 >> 7;
        long rowg = m0 + row;
        int col = (f4 & 127) * 4;
        ushort4 h2 = *(const ushort4*)((const char*)h2r + rowg * 1024 + col * 2);
        ushort4 h1 = *(const ushort4*)((const char*)h1r + rowg * 1024 + col * 2);
        ushort4 hr = *(const ushort4*)((const char*)preb + rowg * 3072 + 1024 + col * 2);
        float4 pv = *(const float4*)(prev + rowg * 512 + col);
        float4 gc = *(const float4*)(g_c + col), bc = *(const float4*)(b_c + col);
        float4 gh = *(const float4*)(g_h + col), bh = *(const float4*)(b_h + col);
        float4 gp = *(const float4*)(g_pre + 512 + col);
        float4 bp = *(const float4*)(b_pre + 512 + col);
        float2 sc = st_c[rowg], sh = st_h[rowg], sp = st_p[rowg];
        auto fuse = [&](unsigned short h2u, unsigned short h1u, unsigned short hru,
                        float pvv, float gcv, float bcv, float ghv, float bhv,
                        float gpv, float bpv) -> float {
            float t2 = (bfu(h2u) - sc.x) * sc.y * gcv + bcv;
            float t1 = (bfu(h1u) - sh.x) * sh.y * ghv + bhv;
            float hg = sigmoid_fast((bfu(hru) - sp.x) * sp.y * gpv + bpv);
            return (1.f - hg) * tanh_fast(t1 + t2) + hg * pvv;
        };
        float4 o;
        o.x = fuse(h2.x, h1.x, hr.x, pv.x, gc.x, bc.x, gh.x, bh.x, gp.x, bp.x);
        o.y = fuse(h2.y, h1.y, hr.y, pv.y, gc.y, bc.y, gh.y, bh.y, gp.y, bp.y);
        o.z = fuse(h2.z, h1.z, hr.z, pv.z, gc.z, bc.z, gh.z, bh.z, gp.z, bp.z);
        o.w = fuse(h2.w, h1.w, hr.w, pv.w, gc.w, bc.w, gh.w, bh.w, gp.w, bp.w);
        *(float4*)(out + rowg * 512 + col) = o;
    }
}

// =============== small kernels ==============================================
__global__ __launch_bounds__(256) void cvt4(
    const float* __restrict__ x, __hip_bfloat16* __restrict__ y, int n4)
{
    int i = blockIdx.x * 256 + threadIdx.x;
    if (i >= n4) return;
    float4 v = ((const float4*)x)[i];
    bfx4 o;
    o.x = __float2bfloat16(v.x); o.y = __float2bfloat16(v.y);
    o.z = __float2bfloat16(v.z); o.w = __float2bfloat16(v.w);
    ((bfx4*)y)[i] = o;
}

__global__ __launch_bounds__(256) void wtrans(
    const float* __restrict__ w0, const float* __restrict__ w1,
    const float* __restrict__ w2, const float* __restrict__ w3,
    const float* __restrict__ w4, __hip_bfloat16* __restrict__ WT)
{
    int z = blockIdx.z;
    const float* W; long off; int N;
    if (z == 0)      { W = w0; off = 0;                N = 1536; }
    else if (z == 1) { W = w1; off = 786432;           N = 512; }
    else if (z == 2) { W = w2; off = 786432 + 262144;  N = 512; }
    else if (z == 3) { W = w3; off = 786432 + 524288;  N = 512; }
    else             { W = w4; off = 786432 + 786432;  N = 512; }
    int n0 = blockIdx.x * 32, k0 = blockIdx.y * 32;
    if (n0 >= N) return;
    __shared__ float t[32][33];
    int tx = threadIdx.x & 31, ty = threadIdx.x >> 5;
#pragma unroll
    for (int i = 0; i < 4; i++)
        t[ty + i * 8][tx] = W[(long)(k0 + ty + i * 8) * N + n0 + tx];
    __syncthreads();
    __hip_bfloat16* O = WT + off;
#pragma unroll
    for (int i = 0; i < 4; i++)
        O[(long)(n0 + ty + i * 8) * 512 + k0 + tx] =
            __float2bfloat16(t[tx][ty + i * 8]);
}

__global__ __launch_bounds__(256) void ptrans(
    const __hip_bfloat16* __restrict__ src, __hip_bfloat16* __restrict__ dst)
{
    long boff = (long)blockIdx.z * (S_ * D_);
    int d0 = blockIdx.x * 32, s0 = blockIdx.y * 32;
    __shared__ __hip_bfloat16 t[32][34];
    int tx = threadIdx.x & 31, ty = threadIdx.x >> 5;
#pragma unroll
    for (int i = 0; i < 4; i++)
        t[ty + i * 8][tx] = src[boff + (long)(s0 + ty + i * 8) * D_ + d0 + tx];
    __syncthreads();
#pragma unroll
    for (int i = 0; i < 4; i++)
        dst[boff + (long)(d0 + ty + i * 8) * S_ + s0 + tx] = t[tx][ty + i * 8];
}

__global__ __launch_bounds__(256) void stats_fin(
    const float2* __restrict__ part, float2* __restrict__ stats)
{
    int r = blockIdx.x * 256 + threadIdx.x;
    float s = 0.f, qq = 0.f;
#pragma unroll
    for (int cb = 0; cb < 12; cb++) {
        float2 v = part[(long)cb * 16384 + r]; s += v.x; qq += v.y;
    }
    float m = s * (1.f / 1536);
    float rs = rsqrtf(qq * (1.f / 1536) - m * m + LN_EPS);
    stats[r] = make_float2(m, rs);
}

// ---------------- chunked SRU scan with inline LN ---------------------------
__global__ __launch_bounds__(256) void scan_part1(
    const __hip_bfloat16* __restrict__ preb, const float2* __restrict__ stats,
    const float* __restrict__ gpre, const float* __restrict__ bpre,
    float* __restrict__ Ap, float* __restrict__ Bp)
{
    int idx = blockIdx.x * 256 + threadIdx.x;   // b*512+d
    int b = idx >> 9, d = idx & 511;
    int ch = blockIdx.y;
    float gz = gpre[d], bz = bpre[d];
    float gp = gpre[1024 + d], bpv = bpre[1024 + d];
    float A = 1.f, s = 0.f;
    for (int t = ch * CT; t < (ch + 1) * CT; t++) {
        long row = (long)t * 32 + b;
        float2 st = stats[row];
        float zr = __bfloat162float(preb[row * 1536 + d]);
        float pr = __bfloat162float(preb[row * 1536 + 1024 + d]);
        float z = sigmoidf_((zr - st.x) * st.y * gz + bz);
        float pl = (pr - st.x) * st.y * gp + bpv;
        float a = 1.f - z;
        A *= a;
        s = a * s + z * pl;
    }
    Ap[ch * 16384 + idx] = A;
    Bp[ch * 16384 + idx] = s;
}

__global__ __launch_bounds__(256) void scan_part2(
    const float* __restrict__ Ap, const float* __restrict__ Bp,
    const float* __restrict__ h0, float* __restrict__ sin_,
    float* __restrict__ hlast)
{
    int idx = blockIdx.x * 256 + threadIdx.x;
    float s = h0[idx];
    for (int ch = 0; ch < NCH; ch++) {
        sin_[ch * 16384 + idx] = s;
        s = Ap[ch * 16384 + idx] * s + Bp[ch * 16384 + idx];
    }
    hlast[idx] = s;
}

__global__ __launch_bounds__(256) void scan_part3(
    const __hip_bfloat16* __restrict__ preb, const float2* __restrict__ stats,
    const float* __restrict__ gpre, const float* __restrict__ bpre,
    const float* __restrict__ sin_, __hip_bfloat16* __restrict__ ssb)
{
    int idx = blockIdx.x * 256 + threadIdx.x;
    int b = idx >> 9, d = idx & 511;
    int ch = blockIdx.y;
    float gz = gpre[d], bz = bpre[d];
    float gp = gpre[1024 + d], bpv = bpre[1024 + d];
    float s = sin_[ch * 16384 + idx];
    for (int t = ch * CT; t < (ch + 1) * CT; t++) {
        long row = (long)t * 32 + b;
        float2 st = stats[row];
        float zr = __bfloat162float(preb[row * 1536 + d]);
        float pr = __bfloat162float(preb[row * 1536 + 1024 + d]);
        float z = sigmoidf_((zr - st.x) * st.y * gz + bz);
        float pl = (pr - st.x) * st.y * gp + bpv;
        s += z * (pl - s);
        ssb[(long)t * 16384 + idx] = __float2bfloat16(s);
    }
}

extern "C" void kernel_launch(void* const* d_in, const int* in_sizes, int n_in,
                              void* d_out, int out_size, void* d_ws, size_t ws_size,
                              hipStream_t stream) {
    const float* prev  = (const float*)d_in[0];
    const float* hid0  = (const float*)d_in[1];
    const float* enc   = (const float*)d_in[2];
    const int*   mlen  = (const int*)  d_in[3];
    const float* W_in  = (const float*)d_in[4];
    const float* W_enc = (const float*)d_in[5];
    const float* W_att = (const float*)d_in[6];
    const float* W_hid = (const float*)d_in[7];
    const float* W_ctx = (const float*)d_in[8];
    const float* g_pre = (const float*)d_in[9];
    const float* b_pre = (const float*)d_in[10];
    const float* g_enc = (const float*)d_in[11];
    const float* b_enc = (const float*)d_in[12];
    const float* g_att = (const float*)d_in[13];
    const float* b_att = (const float*)d_in[14];
    const float* g_h   = (const float*)d_in[15];
    const float* b_h   = (const float*)d_in[16];
    const float* g_c   = (const float*)d_in[17];
    const float* b_c   = (const float*)d_in[18];

    float* out   = (float*)d_out;                 // [T,B,D]
    float* hlast = out + (long)T_ * B_ * D_;      // [B,D]
    float* pattn = hlast + (long)B_ * D_;         // [T,B,S]

    char* ws = (char*)d_ws;
    __hip_bfloat16* preb    = (__hip_bfloat16*)(ws);               // 48MB
    __hip_bfloat16* WT      = (__hip_bfloat16*)(ws + 50331648);    // 4MB
    __hip_bfloat16* prevb   = (__hip_bfloat16*)(ws + 54525952);    // 16MB
    __hip_bfloat16* encb    = (__hip_bfloat16*)(ws + 71303168);    // 16MB
    __hip_bfloat16* pctxb   = (__hip_bfloat16*)(ws + 88080384);    // 16MB
    __hip_bfloat16* pctxT   = (__hip_bfloat16*)(ws + 104857600);   // 16MB
    __hip_bfloat16* ssb     = (__hip_bfloat16*)(ws + 121634816);   // 16MB
    __hip_bfloat16* attninb = (__hip_bfloat16*)(ws + 138412032);   // 16MB
    __hip_bfloat16* pattnb  = (__hip_bfloat16*)(ws + 155189248);   // 16MB (reused as h2raw)
    __hip_bfloat16* attnoutb= (__hip_bfloat16*)(ws + 171966464);   // 16MB
    __hip_bfloat16* h1n     = (__hip_bfloat16*)(ws + 188743680);   // 16MB (h1 RAW now)
    float2* part            = (float2*)(ws + 205520896);           // 1.5MB
    float2* stats           = (float2*)(ws + 207093760);           // 128KB
    float* scanA            = (float*)(ws + 207224832);            // 1MB
    float* scanB            = (float*)(ws + 208273408);            // 1MB
    float* sinb             = (float*)(ws + 209321984);            // 1MB
    float2* stats_enc       = (float2*)(ws + 210370560);           // 128KB
    float2* stats_att       = (float2*)(ws + 210501632);           // 128KB
    float2* stats_h         = (float2*)(ws + 210632704);           // 128KB
    float2* stats_c         = (float2*)(ws + 210763776);           // 128KB

    __hip_bfloat16* h2raw = pattnb;   // pattnb is dead after gemm_av

    const __hip_bfloat16* W_encT = WT + 786432;
    const __hip_bfloat16* W_attT = WT + 786432 + 262144;
    const __hip_bfloat16* W_hidT = WT + 786432 + 524288;
    const __hip_bfloat16* W_ctxT = WT + 786432 + 786432;

    dim3 blk(256);

    // inputs -> bf16
    cvt4<<<8192, blk, 0, stream>>>(prev, prevb, 2097152);
    cvt4<<<8192, blk, 0, stream>>>(enc, encb, 2097152);
    wtrans<<<dim3(48, 16, 5), blk, 0, stream>>>(W_in, W_enc, W_att, W_hid,
                                                W_ctx, WT);

    // K1: preact GEMM -> preb bf16 + LN partials
    gemm_pre<<<dim3(12, 128), blk, 0, stream>>>(prevb, WT, preb, part);
    stats_fin<<<64, blk, 0, stream>>>(part, stats);

    // SRU scan (inline LN on preb)
    scan_part1<<<dim3(64, NCH), blk, 0, stream>>>(preb, stats, g_pre, b_pre,
                                                  scanA, scanB);
    scan_part2<<<64, blk, 0, stream>>>(scanA, scanB, hid0, sinb, hlast);
    scan_part3<<<dim3(64, NCH), blk, 0, stream>>>(preb, stats, g_pre, b_pre,
                                                  sinb, ssb);

    // K2: pctx = LN(enc @ W_enc), via raw + stats + apply
    g128<<<dim3(4, 128), blk, 0, stream>>>(encb, 512, W_encT, 0, pctxb, 1024,
                                           part, 1.f, 1);
    stats4<<<64, blk, 0, stream>>>(part, stats_enc);
    ln_apply<<<4096, blk, 0, stream>>>(pctxb, stats_enc, g_enc, b_enc);
    ptrans<<<dim3(16, 16, 32), blk, 0, stream>>>(pctxb, pctxT);

    // K3: attn_in = LN(ss @ W_attn_in)
    g128<<<dim3(4, 128), blk, 0, stream>>>(ssb, 512, W_attT, 0, attninb, 1024,
                                           part, 1.f, 1);
    stats4<<<64, blk, 0, stream>>>(part, stats_att);
    ln_apply<<<4096, blk, 0, stream>>>(attninb, stats_att, g_att, b_att);

    // K4: align + masked softmax -> pattn fp32 + pattnb bf16
    gemm_attn<<<dim3(1, 16, 32), blk, 0, stream>>>(attninb, pctxb, mlen,
                                                   pattn, pattnb);

    // K5: attn_out = av @ pctx / sqrt(d) -> bf16 (per-batch 128x128)
    g128<<<dim3(4, 4, 32), blk, 0, stream>>>(pattnb, 16384, pctxT, 262144,
                                             attnoutb, 32768, nullptr,
                                             RSQRT_D, 0);

    // K6: h1raw = ss @ W_hidden (LN folded into fin_ep)
    g128<<<dim3(4, 128), blk, 0, stream>>>(ssb, 512, W_hidT, 0, h1n, 1024,
                                           part, 1.f, 1);
    stats4<<<64, blk, 0, stream>>>(part, stats_h);

    // K7: h2raw = attn_out @ W_ctx (LN folded into fin_ep); h2raw = pattnb buf
    g128<<<dim3(4, 128), blk, 0, stream>>>(attnoutb, 512, W_ctxT, 0, h2raw,
                                           1024, part, 1.f, 1);
    stats4<<<64, blk, 0, stream>>>(part, stats_c);

    // final fuse
    fin_ep<<<512, blk, 0, stream>>>(h2raw, h1n, preb, stats_c, stats_h, stats,
                                    g_c, b_c, g_h, b_h, g_pre, b_pre, prev,
                                    out);
}

// Round 5
// 436.164 us; speedup vs baseline: 1.2003x; 1.0283x over previous
//
#include <hip/hip_runtime.h>
#include <hip/hip_bf16.h>
#include <cmath>

#define T_ 512
#define B_ 32
#define S_ 512
#define D_ 512
#define D3_ 1536
#define NCH 16
#define CT (T_ / NCH)
static constexpr float LN_EPS = 1e-6f;
static constexpr float RSQRT_D = 0.044194173824159216f; // 1/sqrt(512)

typedef __attribute__((ext_vector_type(8))) __bf16 bf16x8;
typedef __attribute__((ext_vector_type(4))) float f32x4;

struct __align__(8) bfx4 { __hip_bfloat16 x, y, z, w; };
struct __align__(16) u16x8 { unsigned short h[8]; };

// ---------------- async global->LDS, 16B per lane ---------------------------
__device__ __forceinline__ void g2l16(const void* g, void* l) {
    __builtin_amdgcn_global_load_lds(
        (const __attribute__((address_space(1))) unsigned int*)g,
        (__attribute__((address_space(3))) unsigned int*)l, 16, 0, 0);
}

// 16-lane xor reductions
__device__ __forceinline__ float xr_sum16(float v) {
    v += __shfl_xor(v, 1); v += __shfl_xor(v, 2);
    v += __shfl_xor(v, 4); v += __shfl_xor(v, 8); return v;
}
__device__ __forceinline__ float xr_max16(float v) {
    v = fmaxf(v, __shfl_xor(v, 1)); v = fmaxf(v, __shfl_xor(v, 2));
    v = fmaxf(v, __shfl_xor(v, 4)); v = fmaxf(v, __shfl_xor(v, 8)); return v;
}

__device__ __forceinline__ float sigmoidf_(float x) {
    return 1.f / (1.f + __expf(-x));
}
__device__ __forceinline__ float sigmoid_fast(float x) {
    return __fdividef(1.f, 1.f + __expf(-x));
}
__device__ __forceinline__ float tanh_fast(float x) {
    return 1.f - __fdividef(2.f, __expf(2.f * x) + 1.f);
}
__device__ __forceinline__ float bfu(unsigned short u) {
    unsigned int v = ((unsigned int)u) << 16;
    return __uint_as_float(v);
}

// =============== K1: preact GEMM 128x128, double-buffered ===================
__global__ __launch_bounds__(256) void gemm_pre(
    const __hip_bfloat16* __restrict__ A,
    const __hip_bfloat16* __restrict__ Bw,
    __hip_bfloat16* __restrict__ preb,
    float2* __restrict__ part)
{
    __shared__ char smem[32768];   // 2 x (A 8KB | B 8KB)

    const int lin = blockIdx.y * 12 + blockIdx.x;       // dispatch order
    const int swz = (lin & 7) * 192 + (lin >> 3);       // XCD-contiguous
    const int bx = swz % 12, by = swz / 12;
    const int m0 = by * 128, n0 = bx * 128;
    const int tid = threadIdx.x, lane = tid & 63, w = tid >> 6;
    const int wm = (w >> 1) * 64, wn = (w & 1) * 64;
    const int srow = lane >> 2, skB = (lane & 3) * 16;
    const int q = lane >> 4, c = lane & 15;

    f32x4 acc[4][4];
#pragma unroll
    for (int i = 0; i < 4; i++)
#pragma unroll
        for (int j = 0; j < 4; j++) acc[i][j] = (f32x4)(0.0f);

    const char* ga0 = (const char*)(A + (long)(m0 + w * 16 + srow) * 512) + skB;
    const char* ga1 = (const char*)(A + (long)(m0 + (w + 4) * 16 + srow) * 512) + skB;
    const char* gb0 = (const char*)(Bw + (long)(n0 + w * 16 + srow) * 512) + skB;
    const char* gb1 = (const char*)(Bw + (long)(n0 + (w + 4) * 16 + srow) * 512) + skB;
    char* la0 = smem + w * 1024 + lane * 16;
    char* la1 = smem + (w + 4) * 1024 + lane * 16;
    char* lb0 = smem + 8192 + w * 1024 + lane * 16;
    char* lb1 = smem + 8192 + (w + 4) * 1024 + lane * 16;
    const char* Ar = smem + (wm + c) * 64 + q * 16;
    const char* Br = smem + 8192 + (wn + c) * 64 + q * 16;

    g2l16(ga0, la0);
    g2l16(ga1, la1);
    g2l16(gb0, lb0);
    g2l16(gb1, lb1);
    __syncthreads();

#pragma unroll
    for (int kk = 0; kk < 16; kk++) {
        const int cb = (kk & 1) << 14;
        const int nb = cb ^ 16384;
        if (kk < 15) {
            const long kb = (long)(kk + 1) * 64;
            g2l16(ga0 + kb, la0 + nb);
            g2l16(ga1 + kb, la1 + nb);
            g2l16(gb0 + kb, lb0 + nb);
            g2l16(gb1 + kb, lb1 + nb);
        }
        bf16x8 af[4], bfr[4];
#pragma unroll
        for (int i = 0; i < 4; i++) {
            af[i] = *(const bf16x8*)(Ar + cb + i * 1024);
            bfr[i] = *(const bf16x8*)(Br + cb + i * 1024);
        }
#pragma unroll
        for (int i = 0; i < 4; i++)
#pragma unroll
            for (int j = 0; j < 4; j++)
                acc[i][j] = __builtin_amdgcn_mfma_f32_16x16x32_bf16(
                    af[i], bfr[j], acc[i][j], 0, 0, 0);
        __syncthreads();
    }

    float2* sred = (float2*)smem;        // [128][2]
#pragma unroll
    for (int i = 0; i < 4; i++)
#pragma unroll
        for (int r = 0; r < 4; r++) {
            float s = 0.f, qq = 0.f;
#pragma unroll
            for (int j = 0; j < 4; j++) {
                float v = acc[i][j][r]; s += v; qq += v * v;
            }
            s = xr_sum16(s); qq = xr_sum16(qq);
            if (c == 0) sred[(wm + i * 16 + q * 4 + r) * 2 + (w & 1)] =
                make_float2(s, qq);
        }
    __syncthreads();
    if ((w & 1) == 0 && c == 0) {
#pragma unroll
        for (int i = 0; i < 4; i++)
#pragma unroll
            for (int r = 0; r < 4; r++) {
                int row = wm + i * 16 + q * 4 + r;
                float2 a = sred[row * 2], b2 = sred[row * 2 + 1];
                part[(long)bx * 16384 + m0 + row] =
                    make_float2(a.x + b2.x, a.y + b2.y);
            }
    }
    __syncthreads();

    for (int p = 0; p < 2; p++) {
        if ((w >> 1) == p) {
#pragma unroll
            for (int i = 0; i < 4; i++)
#pragma unroll
                for (int j = 0; j < 4; j++)
#pragma unroll
                    for (int r = 0; r < 4; r++) {
                        int row = i * 16 + q * 4 + r;
                        int col = wn + j * 16 + c;
                        ((__hip_bfloat16*)smem)[row * 128 + col] =
                            __float2bfloat16(acc[i][j][r]);
                    }
        }
        __syncthreads();
#pragma unroll
        for (int rnd = 0; rnd < 4; rnd++) {
            int row = rnd * 16 + (tid >> 4);
            int ch = tid & 15;
            uint4 v = *(const uint4*)(smem + row * 256 + ch * 16);
            long grow = m0 + p * 64 + row;
            *(uint4*)((char*)preb + grow * 3072 + (long)n0 * 2 + ch * 16) = v;
        }
        __syncthreads();
    }
}

// =============== generic 128x128 GEMM (m97 structure) =======================
// A [M,ldaE] bf16 k-major rows; B = weight-like [nN rows, 512 k] bf16.
// Writes bf16(acc*scale) with row byte stride outStrideB + optional row
// (sum,sumsq) partials. z-grid > 1 => per-batch offsets.
__global__ __launch_bounds__(256) void g128(
    const __hip_bfloat16* __restrict__ A, long ldaE,
    const __hip_bfloat16* __restrict__ Bw, long bStrideZ,
    __hip_bfloat16* __restrict__ out, long outStrideB,
    float2* __restrict__ part, float scale, int swizzle)
{
    __shared__ char smem[32768];
    int bx, by;
    if (gridDim.z > 1) {
        bx = blockIdx.x; by = blockIdx.y;
        A += (long)blockIdx.z * 512;
        Bw += (long)blockIdx.z * bStrideZ;
        out += (long)blockIdx.z * 512;
    } else if (swizzle) {
        const int nwg = gridDim.x * gridDim.y;
        const int lin = blockIdx.y * gridDim.x + blockIdx.x;
        const int cpx = nwg >> 3;
        const int swz = (lin & 7) * cpx + (lin >> 3);
        bx = swz % gridDim.x; by = swz / gridDim.x;
    } else { bx = blockIdx.x; by = blockIdx.y; }

    const int m0 = by * 128, n0 = bx * 128;
    const int tid = threadIdx.x, lane = tid & 63, w = tid >> 6;
    const int wm = (w >> 1) * 64, wn = (w & 1) * 64;
    const int srow = lane >> 2, skB = (lane & 3) * 16;
    const int q = lane >> 4, c = lane & 15;

    f32x4 acc[4][4];
#pragma unroll
    for (int i = 0; i < 4; i++)
#pragma unroll
        for (int j = 0; j < 4; j++) acc[i][j] = (f32x4)(0.0f);

    const char* ga0 = (const char*)(A + (long)(m0 + w * 16 + srow) * ldaE) + skB;
    const char* ga1 = (const char*)(A + (long)(m0 + (w + 4) * 16 + srow) * ldaE) + skB;
    const char* gb0 = (const char*)(Bw + (long)(n0 + w * 16 + srow) * 512) + skB;
    const char* gb1 = (const char*)(Bw + (long)(n0 + (w + 4) * 16 + srow) * 512) + skB;
    char* la0 = smem + w * 1024 + lane * 16;
    char* la1 = smem + (w + 4) * 1024 + lane * 16;
    char* lb0 = smem + 8192 + w * 1024 + lane * 16;
    char* lb1 = smem + 8192 + (w + 4) * 1024 + lane * 16;
    const char* Ar = smem + (wm + c) * 64 + q * 16;
    const char* Br = smem + 8192 + (wn + c) * 64 + q * 16;

    g2l16(ga0, la0);
    g2l16(ga1, la1);
    g2l16(gb0, lb0);
    g2l16(gb1, lb1);
    __syncthreads();

#pragma unroll
    for (int kk = 0; kk < 16; kk++) {
        const int cb = (kk & 1) << 14;
        const int nb = cb ^ 16384;
        if (kk < 15) {
            const long kb = (long)(kk + 1) * 64;
            g2l16(ga0 + kb, la0 + nb);
            g2l16(ga1 + kb, la1 + nb);
            g2l16(gb0 + kb, lb0 + nb);
            g2l16(gb1 + kb, lb1 + nb);
        }
        bf16x8 af[4], bfr[4];
#pragma unroll
        for (int i = 0; i < 4; i++) {
            af[i] = *(const bf16x8*)(Ar + cb + i * 1024);
            bfr[i] = *(const bf16x8*)(Br + cb + i * 1024);
        }
#pragma unroll
        for (int i = 0; i < 4; i++)
#pragma unroll
            for (int j = 0; j < 4; j++)
                acc[i][j] = __builtin_amdgcn_mfma_f32_16x16x32_bf16(
                    af[i], bfr[j], acc[i][j], 0, 0, 0);
        __syncthreads();
    }

    if (part) {
        float2* sred = (float2*)smem;    // [128][2]
#pragma unroll
        for (int i = 0; i < 4; i++)
#pragma unroll
            for (int r = 0; r < 4; r++) {
                float s = 0.f, qq = 0.f;
#pragma unroll
                for (int j = 0; j < 4; j++) {
                    float v = acc[i][j][r]; s += v; qq += v * v;
                }
                s = xr_sum16(s); qq = xr_sum16(qq);
                if (c == 0) sred[(wm + i * 16 + q * 4 + r) * 2 + (w & 1)] =
                    make_float2(s, qq);
            }
        __syncthreads();
        if ((w & 1) == 0 && c == 0) {
#pragma unroll
            for (int i = 0; i < 4; i++)
#pragma unroll
                for (int r = 0; r < 4; r++) {
                    int row = wm + i * 16 + q * 4 + r;
                    float2 a = sred[row * 2], b2 = sred[row * 2 + 1];
                    part[(long)bx * 16384 + m0 + row] =
                        make_float2(a.x + b2.x, a.y + b2.y);
                }
        }
        __syncthreads();
    }

    for (int p = 0; p < 2; p++) {
        if ((w >> 1) == p) {
#pragma unroll
            for (int i = 0; i < 4; i++)
#pragma unroll
                for (int j = 0; j < 4; j++)
#pragma unroll
                    for (int r = 0; r < 4; r++) {
                        int row = i * 16 + q * 4 + r;
                        int col = wn + j * 16 + c;
                        ((__hip_bfloat16*)smem)[row * 128 + col] =
                            __float2bfloat16(acc[i][j][r] * scale);
                    }
        }
        __syncthreads();
#pragma unroll
        for (int rnd = 0; rnd < 4; rnd++) {
            int row = rnd * 16 + (tid >> 4);
            int ch = tid & 15;
            uint4 v = *(const uint4*)(smem + row * 256 + ch * 16);
            long grow = m0 + p * 64 + row;
            *(uint4*)((char*)out + grow * outStrideB + (long)n0 * 2 + ch * 16) = v;
        }
        __syncthreads();
    }
}

// =============== K4 core: 32 rows x full N=512, LDS double-buffered =========
#define RC_BUF 34816
__device__ __forceinline__ void rows_core32_lds(
    const __hip_bfloat16* A, long lda,
    const __hip_bfloat16* B, long ldb,
    char* smem, f32x4 (&acc)[2][8])
{
    const int tid = threadIdx.x, lane = tid & 63, w = tid >> 6;
#pragma unroll
    for (int m = 0; m < 2; m++)
#pragma unroll
        for (int j = 0; j < 8; j++) acc[m][j] = (f32x4)(0.0f);

    const char* ga = (const char*)(A + (long)(w * 16 + (lane >> 2)) * lda) + (lane & 3) * 16;
    char* la = smem + w * 1024 + lane * 16;
    const char* gb = (const char*)(B + (long)(w * 128 + (lane >> 2)) * ldb) + (lane & 3) * 16;
    char* lb = smem + 2048 + w * 8192 + lane * 16;
    const long ldbB16 = (long)ldb * 32;
    const char* Ar = smem + (lane & 15) * 64 + (lane >> 4) * 16;
    const char* Br = smem + 2048 + (w * 128 + (lane & 15)) * 64 + (lane >> 4) * 16;

    if (w < 2) g2l16(ga, la);
#pragma unroll
    for (int s = 0; s < 8; s++) g2l16(gb + s * ldbB16, lb + s * 1024);
    __syncthreads();

#pragma unroll
    for (int kk = 0; kk < 16; kk++) {
        const int cb = (kk & 1) * RC_BUF;
        const int nb = ((kk & 1) ^ 1) * RC_BUF;
        if (kk < 15) {
            const long kb = (long)(kk + 1) * 64;
            if (w < 2) g2l16(ga + kb, la + nb);
#pragma unroll
            for (int s = 0; s < 8; s++)
                g2l16(gb + kb + s * ldbB16, lb + nb + s * 1024);
        }
        bf16x8 af[2], bfr[8];
#pragma unroll
        for (int m = 0; m < 2; m++) af[m] = *(const bf16x8*)(Ar + cb + m * 1024);
#pragma unroll
        for (int j = 0; j < 8; j++) bfr[j] = *(const bf16x8*)(Br + cb + j * 1024);
#pragma unroll
        for (int m = 0; m < 2; m++)
#pragma unroll
            for (int j = 0; j < 8; j++)
                acc[m][j] = __builtin_amdgcn_mfma_f32_16x16x32_bf16(
                    af[m], bfr[j], acc[m][j], 0, 0, 0);
        __syncthreads();
    }
}

// =============== K4: align GEMM + masked softmax ============================
__global__ __launch_bounds__(256, 2) void gemm_attn(
    const __hip_bfloat16* __restrict__ attninC2,   // [16384][1024], cols 0-511
    const __hip_bfloat16* __restrict__ pctxb,
    const int* __restrict__ mlen,
    float* __restrict__ pattn, __hip_bfloat16* __restrict__ softb)
{
    __shared__ char smem[69632];
    const int b = blockIdx.z;
    const long t0 = (long)blockIdx.y * 32;
    f32x4 acc[2][8];
    rows_core32_lds(attninC2 + (long)b * 1024 + t0 * 32768, 32768,
                    pctxb + (long)b * 262144, 512, smem, acc);

    const int tid = threadIdx.x, lane = tid & 63, w = tid >> 6;
    const int q = lane >> 4, c = lane & 15;
    const int len = mlen[b];
    float* sred = (float*)smem;          // [32][4]

#pragma unroll
    for (int m = 0; m < 2; m++)
#pragma unroll
        for (int r = 0; r < 4; r++) {
            float mx = -INFINITY;
#pragma unroll
            for (int j = 0; j < 8; j++) {
                int col = w * 128 + j * 16 + c;
                float v = acc[m][j][r] * RSQRT_D;
                acc[m][j][r] = v;
                if (col < len) mx = fmaxf(mx, v);
            }
            mx = xr_max16(mx);
            if (c == 0) sred[(m * 16 + q * 4 + r) * 4 + w] = mx;
        }
    __syncthreads();
    float rmax[2][4];
#pragma unroll
    for (int m = 0; m < 2; m++)
#pragma unroll
        for (int r = 0; r < 4; r++) {
            int row = m * 16 + q * 4 + r;
            rmax[m][r] = fmaxf(fmaxf(sred[row * 4], sred[row * 4 + 1]),
                               fmaxf(sred[row * 4 + 2], sred[row * 4 + 3]));
        }
    __syncthreads();
#pragma unroll
    for (int m = 0; m < 2; m++)
#pragma unroll
        for (int r = 0; r < 4; r++) {
            float s = 0.f;
#pragma unroll
            for (int j = 0; j < 8; j++) {
                int col = w * 128 + j * 16 + c;
                float e = (col < len) ? __expf(acc[m][j][r] - rmax[m][r]) : 0.f;
                acc[m][j][r] = e; s += e;
            }
            s = xr_sum16(s);
            if (c == 0) sred[(m * 16 + q * 4 + r) * 4 + w] = s;
        }
    __syncthreads();
    float rinv[2][4];
#pragma unroll
    for (int m = 0; m < 2; m++)
#pragma unroll
        for (int r = 0; r < 4; r++) {
            int row = m * 16 + q * 4 + r;
            rinv[m][r] = 1.f / (sred[row * 4] + sred[row * 4 + 1] +
                                sred[row * 4 + 2] + sred[row * 4 + 3]);
        }
    __syncthreads();

#pragma unroll
    for (int m = 0; m < 2; m++)
#pragma unroll
        for (int j = 0; j < 8; j++)
#pragma unroll
            for (int r = 0; r < 4; r++) {
                int row = m * 16 + q * 4 + r;
                int col = w * 128 + j * 16 + c;
                float p = acc[m][j][r] * rinv[m][r];
                acc[m][j][r] = p;
                pattn[((t0 + row) * 32 + b) * 512 + col] = p;
                ((__hip_bfloat16*)smem)[row * 512 + col] = __float2bfloat16(p);
            }
    __syncthreads();
#pragma unroll
    for (int rnd = 0; rnd < 8; rnd++) {
        int row = rnd * 4 + w;
        uint4 v = *(const uint4*)(smem + row * 1024 + lane * 16);
        *(uint4*)((char*)softb + ((t0 + row) * 32 + b) * 1024 + lane * 16) = v;
    }
}

// =============== stats reduce (4 partial panels, N=512 LN) ==================
__global__ __launch_bounds__(256) void stats4(
    const float2* __restrict__ part, float2* __restrict__ st)
{
    int r = blockIdx.x * 256 + threadIdx.x;
    float s = 0.f, qq = 0.f;
#pragma unroll
    for (int cb = 0; cb < 4; cb++) {
        float2 v = part[(long)cb * 16384 + r]; s += v.x; qq += v.y;
    }
    float m = s * (1.f / 512);
    float rs = rsqrtf(qq * (1.f / 512) - m * m + LN_EPS);
    st[r] = make_float2(m, rs);
}

// =============== strided LayerNorm apply (C2 attn_in half) ==================
__global__ __launch_bounds__(256) void ln_apply_s(
    __hip_bfloat16* __restrict__ x,          // [16384][1024], cols 0-511
    const float2* __restrict__ st,
    const float* __restrict__ g, const float* __restrict__ bb)
{
    int i = blockIdx.x * 256 + threadIdx.x;   // 16B chunk id; 64 per row; 1M total
    int row = i >> 6;
    int c0 = (i & 63) * 8;
    float2 s = st[row];
    char* p = (char*)x + (long)row * 2048 + (long)(i & 63) * 16;
    u16x8 v = *(const u16x8*)p;
    float4 g0 = *(const float4*)(g + c0), g1 = *(const float4*)(g + c0 + 4);
    float4 b0 = *(const float4*)(bb + c0), b1 = *(const float4*)(bb + c0 + 4);
    float gv[8] = {g0.x, g0.y, g0.z, g0.w, g1.x, g1.y, g1.z, g1.w};
    float bv[8] = {b0.x, b0.y, b0.z, b0.w, b1.x, b1.y, b1.z, b1.w};
#pragma unroll
    for (int k = 0; k < 8; k++) {
        float f = (bfu(v.h[k]) - s.x) * s.y * gv[k] + bv[k];
        v.h[k] = __hip_bfloat16_raw(__float2bfloat16(f)).x;
    }
    *(u16x8*)p = v;
}

// =============== LN + dual-write (normalized + transposed) for pctx =========
__global__ __launch_bounds__(256) void lnt(
    __hip_bfloat16* __restrict__ x,          // raw pctx [B*S][512], in-place LN
    __hip_bfloat16* __restrict__ xT,         // [B][512][S]
    const float2* __restrict__ st,
    const float* __restrict__ g, const float* __restrict__ bb)
{
    long boff = (long)blockIdx.z * (S_ * D_);
    int d0 = blockIdx.x * 32, s0 = blockIdx.y * 32;
    __shared__ __hip_bfloat16 t[32][34];
    int tx = threadIdx.x & 31, ty = threadIdx.x >> 5;
    float gv = g[d0 + tx], bv = bb[d0 + tx];
#pragma unroll
    for (int i = 0; i < 4; i++) {
        int srow = s0 + ty + i * 8;
        long row = (long)blockIdx.z * S_ + srow;
        float2 s = st[row];
        float f = (bfu(__hip_bfloat16_raw(x[boff + (long)srow * D_ + d0 + tx]).x)
                   - s.x) * s.y * gv + bv;
        __hip_bfloat16 h = __float2bfloat16(f);
        t[ty + i * 8][tx] = h;
        x[boff + (long)srow * D_ + d0 + tx] = h;
    }
    __syncthreads();
#pragma unroll
    for (int i = 0; i < 4; i++)
        xT[boff + (long)(d0 + ty + i * 8) * S_ + s0 + tx] = t[tx][ty + i * 8];
}

// =============== final elementwise fuse =====================================
// out = (1-hg)*tanh(LN_h(h1raw) + LN_c(h2raw)) + hg*prev
__global__ __launch_bounds__(256) void fin_ep(
    const __hip_bfloat16* __restrict__ h2r,   // [16384][512]
    const __hip_bfloat16* __restrict__ C2,    // [16384][1024], h1raw cols 512+
    const __hip_bfloat16* __restrict__ preb,
    const float2* __restrict__ st_c, const float2* __restrict__ st_h,
    const float2* __restrict__ st_p,
    const float* __restrict__ g_c, const float* __restrict__ b_c,
    const float* __restrict__ g_h, const float* __restrict__ b_h,
    const float* __restrict__ g_pre, const float* __restrict__ b_pre,
    const float* __restrict__ prev, float* __restrict__ out)
{
    const long m0 = (long)blockIdx.x * 32;
    const int tid = threadIdx.x;
#pragma unroll
    for (int ch = 0; ch < 16; ch++) {
        int f4 = ch * 256 + tid;             // 0..4095
        int row = f4 >> 7;
        long rowg = m0 + row;
        int col = (f4 & 127) * 4;
        ushort4 h2 = *(const ushort4*)((const char*)h2r + rowg * 1024 + col * 2);
        ushort4 h1 = *(const ushort4*)((const char*)C2 + rowg * 2048 + 1024 + col * 2);
        ushort4 hr = *(const ushort4*)((const char*)preb + rowg * 3072 + 1024 + col * 2);
        float4 pv = *(const float4*)(prev + rowg * 512 + col);
        float4 gc = *(const float4*)(g_c + col), bc = *(const float4*)(b_c + col);
        float4 gh = *(const float4*)(g_h + col), bh = *(const float4*)(b_h + col);
        float4 gp = *(const float4*)(g_pre + 512 + col);
        float4 bp = *(const float4*)(b_pre + 512 + col);
        float2 sc = st_c[rowg], sh = st_h[rowg], sp = st_p[rowg];
        auto fuse = [&](unsigned short h2u, unsigned short h1u, unsigned short hru,
                        float pvv, float gcv, float bcv, float ghv, float bhv,
                        float gpv, float bpv) -> float {
            float t2 = (bfu(h2u) - sc.x) * sc.y * gcv + bcv;
            float t1 = (bfu(h1u) - sh.x) * sh.y * ghv + bhv;
            float hg = sigmoid_fast((bfu(hru) - sp.x) * sp.y * gpv + bpv);
            return (1.f - hg) * tanh_fast(t1 + t2) + hg * pvv;
        };
        float4 o;
        o.x = fuse(h2.x, h1.x, hr.x, pv.x, gc.x, bc.x, gh.x, bh.x, gp.x, bp.x);
        o.y = fuse(h2.y, h1.y, hr.y, pv.y, gc.y, bc.y, gh.y, bh.y, gp.y, bp.y);
        o.z = fuse(h2.z, h1.z, hr.z, pv.z, gc.z, bc.z, gh.z, bh.z, gp.z, bp.z);
        o.w = fuse(h2.w, h1.w, hr.w, pv.w, gc.w, bc.w, gh.w, bh.w, gp.w, bp.w);
        *(float4*)(out + rowg * 512 + col) = o;
    }
}

// =============== small kernels ==============================================
__global__ __launch_bounds__(256) void cvt4(
    const float* __restrict__ x, __hip_bfloat16* __restrict__ y, int n4)
{
    int i = blockIdx.x * 256 + threadIdx.x;
    if (i >= n4) return;
    float4 v = ((const float4*)x)[i];
    bfx4 o;
    o.x = __float2bfloat16(v.x); o.y = __float2bfloat16(v.y);
    o.z = __float2bfloat16(v.z); o.w = __float2bfloat16(v.w);
    ((bfx4*)y)[i] = o;
}

__global__ __launch_bounds__(256) void wtrans(
    const float* __restrict__ w0, const float* __restrict__ w1,
    const float* __restrict__ w2, const float* __restrict__ w3,
    const float* __restrict__ w4, __hip_bfloat16* __restrict__ WT)
{
    int z = blockIdx.z;
    const float* W; long off; int N;
    if (z == 0)      { W = w0; off = 0;                N = 1536; }
    else if (z == 1) { W = w1; off = 786432;           N = 512; }
    else if (z == 2) { W = w2; off = 786432 + 262144;  N = 512; }
    else if (z == 3) { W = w3; off = 786432 + 524288;  N = 512; }
    else             { W = w4; off = 786432 + 786432;  N = 512; }
    int n0 = blockIdx.x * 32, k0 = blockIdx.y * 32;
    if (n0 >= N) return;
    __shared__ float t[32][33];
    int tx = threadIdx.x & 31, ty = threadIdx.x >> 5;
#pragma unroll
    for (int i = 0; i < 4; i++)
        t[ty + i * 8][tx] = W[(long)(k0 + ty + i * 8) * N + n0 + tx];
    __syncthreads();
    __hip_bfloat16* O = WT + off;
#pragma unroll
    for (int i = 0; i < 4; i++)
        O[(long)(n0 + ty + i * 8) * 512 + k0 + tx] =
            __float2bfloat16(t[tx][ty + i * 8]);
}

__global__ __launch_bounds__(256) void stats_fin(
    const float2* __restrict__ part, float2* __restrict__ stats)
{
    int r = blockIdx.x * 256 + threadIdx.x;
    float s = 0.f, qq = 0.f;
#pragma unroll
    for (int cb = 0; cb < 12; cb++) {
        float2 v = part[(long)cb * 16384 + r]; s += v.x; qq += v.y;
    }
    float m = s * (1.f / 1536);
    float rs = rsqrtf(qq * (1.f / 1536) - m * m + LN_EPS);
    stats[r] = make_float2(m, rs);
}

// ---------------- chunked SRU scan with inline LN (2 d-lanes/thread) --------
__global__ __launch_bounds__(256) void scan_part1(
    const __hip_bfloat16* __restrict__ preb, const float2* __restrict__ stats,
    const float* __restrict__ gpre, const float* __restrict__ bpre,
    float* __restrict__ Ap, float* __restrict__ Bp)
{
    int i2 = blockIdx.x * 256 + threadIdx.x;    // 0..8191
    int b = i2 >> 8, d = (i2 & 255) * 2;
    int idx = b * 512 + d;
    int ch = blockIdx.y;
    float2 gz = *(const float2*)(gpre + d), bz = *(const float2*)(bpre + d);
    float2 gp = *(const float2*)(gpre + 1024 + d);
    float2 bp = *(const float2*)(bpre + 1024 + d);
    float A0 = 1.f, s0 = 0.f, A1 = 1.f, s1 = 0.f;
    for (int t = ch * CT; t < (ch + 1) * CT; t++) {
        long row = (long)t * 32 + b;
        float2 st = stats[row];
        ushort2 zr = *(const ushort2*)(preb + row * 1536 + d);
        ushort2 pr = *(const ushort2*)(preb + row * 1536 + 1024 + d);
        float z0 = sigmoidf_((bfu(zr.x) - st.x) * st.y * gz.x + bz.x);
        float z1 = sigmoidf_((bfu(zr.y) - st.x) * st.y * gz.y + bz.y);
        float p0 = (bfu(pr.x) - st.x) * st.y * gp.x + bp.x;
        float p1 = (bfu(pr.y) - st.x) * st.y * gp.y + bp.y;
        A0 *= (1.f - z0); s0 = (1.f - z0) * s0 + z0 * p0;
        A1 *= (1.f - z1); s1 = (1.f - z1) * s1 + z1 * p1;
    }
    *(float2*)(Ap + ch * 16384 + idx) = make_float2(A0, A1);
    *(float2*)(Bp + ch * 16384 + idx) = make_float2(s0, s1);
}

__global__ __launch_bounds__(256) void scan_part2(
    const float* __restrict__ Ap, const float* __restrict__ Bp,
    const float* __restrict__ h0, float* __restrict__ sin_,
    float* __restrict__ hlast)
{
    int idx = blockIdx.x * 256 + threadIdx.x;
    float s = h0[idx];
    for (int ch = 0; ch < NCH; ch++) {
        sin_[ch * 16384 + idx] = s;
        s = Ap[ch * 16384 + idx] * s + Bp[ch * 16384 + idx];
    }
    hlast[idx] = s;
}

__global__ __launch_bounds__(256) void scan_part3(
    const __hip_bfloat16* __restrict__ preb, const float2* __restrict__ stats,
    const float* __restrict__ gpre, const float* __restrict__ bpre,
    const float* __restrict__ sin_, __hip_bfloat16* __restrict__ ssb)
{
    int i2 = blockIdx.x * 256 + threadIdx.x;    // 0..8191
    int b = i2 >> 8, d = (i2 & 255) * 2;
    int idx = b * 512 + d;
    int ch = blockIdx.y;
    float2 gz = *(const float2*)(gpre + d), bz = *(const float2*)(bpre + d);
    float2 gp = *(const float2*)(gpre + 1024 + d);
    float2 bp = *(const float2*)(bpre + 1024 + d);
    float2 sv = *(const float2*)(sin_ + ch * 16384 + idx);
    float s0 = sv.x, s1 = sv.y;
    for (int t = ch * CT; t < (ch + 1) * CT; t++) {
        long row = (long)t * 32 + b;
        float2 st = stats[row];
        ushort2 zr = *(const ushort2*)(preb + row * 1536 + d);
        ushort2 pr = *(const ushort2*)(preb + row * 1536 + 1024 + d);
        float z0 = sigmoidf_((bfu(zr.x) - st.x) * st.y * gz.x + bz.x);
        float z1 = sigmoidf_((bfu(zr.y) - st.x) * st.y * gz.y + bz.y);
        float p0 = (bfu(pr.x) - st.x) * st.y * gp.x + bp.x;
        float p1 = (bfu(pr.y) - st.x) * st.y * gp.y + bp.y;
        s0 += z0 * (p0 - s0);
        s1 += z1 * (p1 - s1);
        ushort2 o;
        o.x = __hip_bfloat16_raw(__float2bfloat16(s0)).x;
        o.y = __hip_bfloat16_raw(__float2bfloat16(s1)).x;
        *(ushort2*)(ssb + (long)t * 16384 + idx) = o;
    }
}

extern "C" void kernel_launch(void* const* d_in, const int* in_sizes, int n_in,
                              void* d_out, int out_size, void* d_ws, size_t ws_size,
                              hipStream_t stream) {
    const float* prev  = (const float*)d_in[0];
    const float* hid0  = (const float*)d_in[1];
    const float* enc   = (const float*)d_in[2];
    const int*   mlen  = (const int*)  d_in[3];
    const float* W_in  = (const float*)d_in[4];
    const float* W_enc = (const float*)d_in[5];
    const float* W_att = (const float*)d_in[6];
    const float* W_hid = (const float*)d_in[7];
    const float* W_ctx = (const float*)d_in[8];
    const float* g_pre = (const float*)d_in[9];
    const float* b_pre = (const float*)d_in[10];
    const float* g_enc = (const float*)d_in[11];
    const float* b_enc = (const float*)d_in[12];
    const float* g_att = (const float*)d_in[13];
    const float* b_att = (const float*)d_in[14];
    const float* g_h   = (const float*)d_in[15];
    const float* b_h   = (const float*)d_in[16];
    const float* g_c   = (const float*)d_in[17];
    const float* b_c   = (const float*)d_in[18];

    float* out   = (float*)d_out;                 // [T,B,D]
    float* hlast = out + (long)T_ * B_ * D_;      // [B,D]
    float* pattn = hlast + (long)B_ * D_;         // [T,B,S]

    char* ws = (char*)d_ws;
    __hip_bfloat16* preb    = (__hip_bfloat16*)(ws);               // 48MB
    __hip_bfloat16* WT      = (__hip_bfloat16*)(ws + 50331648);    // 4MB
    __hip_bfloat16* prevb   = (__hip_bfloat16*)(ws + 54525952);    // 16MB
    __hip_bfloat16* encb    = (__hip_bfloat16*)(ws + 71303168);    // 16MB
    __hip_bfloat16* pctxb   = (__hip_bfloat16*)(ws + 88080384);    // 16MB
    __hip_bfloat16* pctxT   = (__hip_bfloat16*)(ws + 104857600);   // 16MB
    __hip_bfloat16* ssb     = (__hip_bfloat16*)(ws + 121634816);   // 16MB
    __hip_bfloat16* C2      = (__hip_bfloat16*)(ws + 138412032);   // 32MB [16384][1024]
    __hip_bfloat16* attnoutb= (__hip_bfloat16*)(ws + 171966464);   // 16MB
    __hip_bfloat16* softb   = (__hip_bfloat16*)(ws + 188743680);   // 16MB (softmax bf16)
    float2* part            = (float2*)(ws + 205520896);           // 1.5MB
    float2* stats           = (float2*)(ws + 207093760);           // 128KB
    float* scanA            = (float*)(ws + 207224832);            // 1MB
    float* scanB            = (float*)(ws + 208273408);            // 1MB
    float* sinb             = (float*)(ws + 209321984);            // 1MB
    float2* stats_enc       = (float2*)(ws + 210370560);           // 128KB
    float2* stats_att       = (float2*)(ws + 210501632);           // 128KB
    float2* stats_h         = (float2*)(ws + 210632704);           // 128KB
    float2* stats_c         = (float2*)(ws + 210763776);           // 128KB

    __hip_bfloat16* h2raw = softb;   // softb dead after gemm_av; reuse for h2

    const __hip_bfloat16* W_encT = WT + 786432;
    const __hip_bfloat16* W_attT = WT + 786432 + 262144;   // [W_att|W_hid] adjacent
    const __hip_bfloat16* W_ctxT = WT + 786432 + 786432;

    dim3 blk(256);

    // inputs -> bf16
    cvt4<<<8192, blk, 0, stream>>>(prev, prevb, 2097152);
    cvt4<<<8192, blk, 0, stream>>>(enc, encb, 2097152);
    wtrans<<<dim3(48, 16, 5), blk, 0, stream>>>(W_in, W_enc, W_att, W_hid,
                                                W_ctx, WT);

    // K1: preact GEMM -> preb bf16 + LN partials
    gemm_pre<<<dim3(12, 128), blk, 0, stream>>>(prevb, WT, preb, part);
    stats_fin<<<64, blk, 0, stream>>>(part, stats);

    // SRU scan (inline LN on preb)
    scan_part1<<<dim3(32, NCH), blk, 0, stream>>>(preb, stats, g_pre, b_pre,
                                                  scanA, scanB);
    scan_part2<<<64, blk, 0, stream>>>(scanA, scanB, hid0, sinb, hlast);
    scan_part3<<<dim3(32, NCH), blk, 0, stream>>>(preb, stats, g_pre, b_pre,
                                                  sinb, ssb);

    // K2: pctx raw GEMM -> stats -> LN + transpose (one pass)
    g128<<<dim3(4, 128), blk, 0, stream>>>(encb, 512, W_encT, 0, pctxb, 1024,
                                           part, 1.f, 1);
    stats4<<<64, blk, 0, stream>>>(part, stats_enc);
    lnt<<<dim3(16, 16, 32), blk, 0, stream>>>(pctxb, pctxT, stats_enc,
                                              g_enc, b_enc);

    // K3+K6 merged: [attn_in raw | h1 raw] = ss @ [W_att|W_hid]  (N=1024)
    g128<<<dim3(8, 128), blk, 0, stream>>>(ssb, 512, W_attT, 0, C2, 2048,
                                           part, 1.f, 1);
    stats4<<<64, blk, 0, stream>>>(part, stats_att);
    stats4<<<64, blk, 0, stream>>>(part + 4 * 16384, stats_h);
    ln_apply_s<<<4096, blk, 0, stream>>>(C2, stats_att, g_att, b_att);

    // K4: align + masked softmax -> pattn fp32 + softb bf16
    gemm_attn<<<dim3(1, 16, 32), blk, 0, stream>>>(C2, pctxb, mlen,
                                                   pattn, softb);

    // K5: attn_out = av @ pctx / sqrt(d) -> bf16 (per-batch 128x128)
    g128<<<dim3(4, 4, 32), blk, 0, stream>>>(softb, 16384, pctxT, 262144,
                                             attnoutb, 32768, nullptr,
                                             RSQRT_D, 0);

    // K7: h2raw = attn_out @ W_ctx (LN folded into fin_ep); reuses softb buf
    g128<<<dim3(4, 128), blk, 0, stream>>>(attnoutb, 512, W_ctxT, 0, h2raw,
                                           1024, part, 1.f, 1);
    stats4<<<64, blk, 0, stream>>>(part, stats_c);

    // final fuse
    fin_ep<<<512, blk, 0, stream>>>(h2raw, C2, preb, stats_c, stats_h, stats,
                                    g_c, b_c, g_h, b_h, g_pre, b_pre, prev,
                                    out);
}